// Round 12
// baseline (184.420 us; speedup 1.0000x reference)
//
#include <hip/hip_runtime.h>
#include <cstdint>
#include <cstddef>

#define B_ 256
#define IW_ 3072
#define L_ 8
#define NN_ 7
#define FCIN_ 16384
#define OUTW_ 10
#define ICST 40            // ushorts per (row,col) cell: 32 ic + 8 pad
#define YPLANE (324 * ICST)
#define WCH 36864          // ushorts per (l,icc) conv2 weight chunk: [plane2][tap9][mt4][lane64][j8]

typedef short short8 __attribute__((ext_vector_type(8)));
typedef float f32x4 __attribute__((ext_vector_type(4)));

__device__ __forceinline__ ushort f2bf(float x) {
    uint u = __float_as_uint(x);
    return (ushort)((u + 0x7fffu + ((u >> 16) & 1u)) >> 16);
}
__device__ __forceinline__ float bf2f(ushort b) { return __uint_as_float(((uint)b) << 16); }

// ---------- repack conv1 weights into MFMA frag-linear hi/lo bf16 ----------
__global__ void k_repack_w1f(const float* __restrict__ w1, ushort* __restrict__ w1fh,
                             ushort* __restrict__ w1fl) {
    int i = blockIdx.x * 256 + threadIdx.x;
    if (i >= 16384) return;
    int j    = i & 7;
    int lane = (i >> 3) & 63;
    int mt   = (i >> 9) & 3;
    int l    = i >> 11;
    int fr = lane & 15, fq = lane >> 4;
    int oc = mt * 16 + fr;
    int k = fq * 8 + j;
    float w = (k < 27) ? w1[(size_t)(l * 64 + oc) * 27 + k] : 0.f;
    ushort hb = f2bf(w);
    w1fh[i] = hb;
    w1fl[i] = f2bf(w - bf2f(hb));
}

// ---------- repack conv2 weights: single buffer [l8][icc2][plane2][tap9][mt4][lane64][j8] ----------
__global__ void k_repack_w2(const float* __restrict__ w2, ushort* __restrict__ w2hl) {
    int i = blockIdx.x * 256 + threadIdx.x;
    if (i >= 589824) return;
    int j     = i & 7;
    int lane  = (i >> 3) & 63;
    int mt    = (i >> 9) & 3;
    int tap   = (i >> 11) % 9;
    int plane = (i / 18432) & 1;
    int icc   = (i / 36864) & 1;
    int l     = i / 73728;
    int fr = lane & 15, fq = lane >> 4;
    int oc = mt * 16 + fr;
    int ic = icc * 32 + fq * 8 + j;
    float w = w2[(((size_t)l * 64 + oc) * 64 + ic) * 9 + tap];
    ushort hb = f2bf(w);
    w2hl[i] = plane ? f2bf(w - bf2f(hb)) : hb;
}

// ---------- mixture ----------
__global__ __launch_bounds__(256) void k_mixture(const float* __restrict__ x, const float* __restrict__ nw,
                                                 const float* __restrict__ nb, float* __restrict__ mix) {
    __shared__ float red[4 * NN_];
    __shared__ float bes[NN_];
    int b = blockIdx.x, tid = threadIdx.x;
    const float* xb = x + (size_t)b * IW_;
    float p[NN_];
#pragma unroll
    for (int n = 0; n < NN_; ++n) p[n] = 0.f;
    for (int i = tid; i < IW_; i += 256) {
        float xv = xb[i];
#pragma unroll
        for (int n = 0; n < NN_; ++n) p[n] = fmaf(xv, nw[n * IW_ + i], p[n]);
    }
#pragma unroll
    for (int n = 0; n < NN_; ++n) {
        float v = p[n];
        for (int off = 32; off > 0; off >>= 1) v += __shfl_xor(v, off);
        if ((tid & 63) == 0) red[(tid >> 6) * NN_ + n] = v;
    }
    __syncthreads();
    if (tid < NN_) {
        float s = red[tid] + red[NN_ + tid] + red[2 * NN_ + tid] + red[3 * NN_ + tid] + nb[tid];
        bes[tid] = 1.f / (1.f + expf(-s));
    }
    __syncthreads();
    if (tid < L_) {
        int leaf = tid;
        float b0 = bes[0];
        float t0 = ((leaf >> 2) & 1) ? b0 : 1.f - b0;
        float b1v = bes[1 + ((leaf >> 2) & 1)];
        float t1 = ((leaf >> 1) & 1) ? b1v : 1.f - b1v;
        float b2v = bes[3 + ((leaf >> 1) & 3)];
        float t2 = (leaf & 1) ? b2v : 1.f - b2v;
        mix[b * L_ + leaf] = t0 * t1 * t2;
    }
}

// ---------- fused conv1/conv2: double-buffered y + wave-parity phase stagger ----------
// block = sample (grid 256 = 1/CU), 512 thr / 8 waves, 16 steps.
// Phase A (long): stage-issue(s+1) ; odd waves {conv2(s); conv1(s+1)}, even waves {conv1(s+1); conv2(s)}
//   -> at any instant each SIMD's 2 waves are in OPPOSITE phases (MFMA vs VALU co-issue).
// Phase B (short): ds_write staged W2 chunk. conv1 writes y[(s+1)&1], conv2 reads y[s&1].
__global__ __launch_bounds__(512, 2) void k_fused(const float* __restrict__ x,
                                                  const ushort* __restrict__ w1fh, const ushort* __restrict__ w1fl,
                                                  const float* __restrict__ cb1,
                                                  const ushort* __restrict__ w2hl,
                                                  const float* __restrict__ cb2, const float* __restrict__ mixw,
                                                  float* __restrict__ out1, int boff) {
    __shared__ __align__(16) ushort smem[2 * YPLANE + WCH];   // y0|y1 51.8 KB + w 72 KB = 123.8 KB
    ushort* wlds = smem + 2 * YPLANE;
    float* xpad = (float*)smem;                                // prologue-only alias (13.9 KB < y0)

    int tid = threadIdx.x;
    int bl = blockIdx.x;
    int b = boff + bl;
    int lane = tid & 63, wid = tid >> 6;
    int fr = lane & 15, fq = lane >> 4;
    int g = wid & 1, ng = wid >> 1;               // conv2: mts {2g,2g+1}, rows {4ng..4ng+3}

    // ---- prologue: xpad zero + fill ----
    for (int i = tid; i < 3 * 34 * 34; i += 512) xpad[i] = 0.f;
    __syncthreads();
    for (int i = tid; i < 3072; i += 512) {
        int ch = i >> 10, rr = (i >> 5) & 31, cc = i & 31;
        xpad[(ch * 34 + rr + 1) * 34 + cc + 1] = x[(size_t)b * IW_ + i];
    }
    __syncthreads();

    // ---- leaf-invariant conv1 im2col B-frags, single bf16 (RTN) ----
    short8 Bh[8];
#pragma unroll
    for (int i = 0; i < 8; ++i) {
        int nt = wid * 8 + i;
        int pos = nt * 16 + fr;          // pre-pool position, row-major 32x32
        int r = pos >> 5, c = pos & 31;
#pragma unroll
        for (int j = 0; j < 8; ++j) {
            int k = fq * 8 + j;          // k = ic*9 + tap
            float xv = 0.f;
            if (k < 27) {
                int ic = k / 9;
                int tap = k - ic * 9;
                int dr = tap / 3, dc = tap - dr * 3;
                xv = xpad[(ic * 34 + r + dr) * 34 + (c + dc)];
            }
            Bh[i][j] = (short)f2bf(xv);
        }
    }
    __syncthreads();
    {   // zero BOTH y planes (borders stay zero forever)
        uint4 z; z.x = z.y = z.z = z.w = 0u;
        for (int i = tid; i < (2 * YPLANE) / 8; i += 512) ((uint4*)smem)[i] = z;
    }
    __syncthreads();

    f32x4 acc[2][4], oacc[2][4];
#pragma unroll
    for (int m = 0; m < 2; ++m)
#pragma unroll
        for (int rl = 0; rl < 4; ++rl) { acc[m][rl] = (f32x4)0.f; oacc[m][rl] = (f32x4)0.f; }

    uint4 stg[9];
    auto STAGE_ISSUE = [&](int s) {
        const uint4* wsrc = (const uint4*)(w2hl + (size_t)s * WCH);   // s = (l*2+icc)
#pragma unroll
        for (int r = 0; r < 9; ++r) stg[r] = wsrc[r * 512 + tid];
    };
    auto STAGE_WRITE = [&]() {
#pragma unroll
        for (int r = 0; r < 9; ++r) *(uint4*)&wlds[(r * 512 + tid) * 8] = stg[r];
    };

    auto CONV1 = [&](int s) {   // writes y[s&1]
        int l = s >> 1, icc = s & 1;
        ushort* yt = smem + (size_t)(s & 1) * YPLANE;
#pragma unroll
        for (int mt2 = 0; mt2 < 2; ++mt2) {
            int mtg = icc * 2 + mt2;
            short8 ah = *(const short8*)(w1fh + ((size_t)(l * 4 + mtg) * 64 + lane) * 8);
            short8 al = *(const short8*)(w1fl + ((size_t)(l * 4 + mtg) * 64 + lane) * 8);
            f32x4 a1[8];
#pragma unroll
            for (int i = 0; i < 8; ++i) {
                f32x4 t = (f32x4)0.f;
                t = __builtin_amdgcn_mfma_f32_16x16x32_bf16(ah, Bh[i], t, 0, 0, 0);
                t = __builtin_amdgcn_mfma_f32_16x16x32_bf16(al, Bh[i], t, 0, 0, 0);
                a1[i] = t;
            }
            float4 bias4 = *(const float4*)(cb1 + l * 64 + mtg * 16 + fq * 4);
            float bb[4] = {bias4.x, bias4.y, bias4.z, bias4.w};
#pragma unroll
            for (int g4 = 0; g4 < 4; ++g4) {
                int i = (g4 & 1) + (g4 >> 1) * 4;   // {0,1,4,5}; pool partner i+2
                ushort hb[4];
#pragma unroll
                for (int j2 = 0; j2 < 4; ++j2) {
                    float m0 = fmaxf(a1[i][j2], a1[i + 2][j2]);
                    float m1 = fmaxf(m0, __shfl_xor(m0, 1));
                    float v = fmaxf(m1 + bb[j2], 0.f);
                    hb[j2] = f2bf(v);
                }
                if ((fr & 1) == 0) {
                    int pr = 2 * wid + (i >> 2);
                    int pc = ((i & 1) * 16 + fr) >> 1;
                    int off = ((pr + 1) * 18 + (pc + 1)) * ICST + mt2 * 16 + fq * 4;
                    uint2 H;
                    H.x = (uint)hb[0] | ((uint)hb[1] << 16);
                    H.y = (uint)hb[2] | ((uint)hb[3] << 16);
                    *(uint2*)&yt[off] = H;
                }
            }
        }
    };

    auto CONV2 = [&](int s) {   // reads y[s&1] + wlds
        int l = s >> 1, icc = s & 1;
        const ushort* yt = smem + (size_t)(s & 1) * YPLANE;
#pragma unroll
        for (int dc = 0; dc < 3; ++dc) {
            short8 Ah[2][3], Al[2][3];
#pragma unroll
            for (int dr = 0; dr < 3; ++dr) {
                int tap = dr * 3 + dc;
#pragma unroll
                for (int m = 0; m < 2; ++m) {
                    int mt = 2 * g + m;
                    Ah[m][dr] = *(const short8*)&wlds[((tap * 4 + mt) * 64 + lane) * 8];
                    Al[m][dr] = *(const short8*)&wlds[(((9 + tap) * 4 + mt) * 64 + lane) * 8];
                }
            }
#pragma unroll
            for (int rr = 0; rr < 6; ++rr) {
                int off = ((4 * ng + rr) * 18 + (fr + dc)) * ICST + fq * 8;
                short8 bh = *(const short8*)(yt + off);
#pragma unroll
                for (int dr = 0; dr < 3; ++dr) {
                    int rl = rr - dr;
                    if (rl >= 0 && rl < 4) {
#pragma unroll
                        for (int m = 0; m < 2; ++m) {
                            acc[m][rl] = __builtin_amdgcn_mfma_f32_16x16x32_bf16(Ah[m][dr], bh, acc[m][rl], 0, 0, 0);
                            acc[m][rl] = __builtin_amdgcn_mfma_f32_16x16x32_bf16(Al[m][dr], bh, acc[m][rl], 0, 0, 0);
                        }
                    }
                }
            }
        }
        if (icc) {  // leaf epilogue: bias + relu + mixture accumulate
            float mx = mixw[(size_t)b * 8 + l];
#pragma unroll
            for (int m = 0; m < 2; ++m)
#pragma unroll
                for (int j = 0; j < 4; ++j) {
                    float bias = cb2[l * 64 + (2 * g + m) * 16 + fq * 4 + j];
#pragma unroll
                    for (int rl = 0; rl < 4; ++rl) {
                        float v = fmaxf(acc[m][rl][j] + bias, 0.f);
                        oacc[m][rl][j] = fmaf(mx, v, oacc[m][rl][j]);
                        acc[m][rl][j] = 0.f;
                    }
                }
        }
    };

    // ---- pipeline prologue: stage(0) + conv1(0) + publish w(0) ----
    STAGE_ISSUE(0);
    CONV1(0);
    STAGE_WRITE();
    __syncthreads();

    for (int s = 0; s < 16; ++s) {
        if (s < 15) STAGE_ISSUE(s + 1);
        if (wid & 1) {
            CONV2(s);
            if (s < 15) CONV1(s + 1);
        } else {
            if (s < 15) CONV1(s + 1);
            CONV2(s);
        }
        __syncthreads();
        if (s < 15) {
            STAGE_WRITE();
            __syncthreads();
        }
    }

    // ---- store out1 [bl][64 oc][256 pos] fp32 ----
#pragma unroll
    for (int m = 0; m < 2; ++m)
#pragma unroll
        for (int rl = 0; rl < 4; ++rl)
#pragma unroll
            for (int j = 0; j < 4; ++j) {
                int oc = (2 * g + m) * 16 + fq * 4 + j;
                int pos = (4 * ng + rl) * 16 + fr;
                out1[((size_t)bl * 64 + oc) * 256 + pos] = oacc[m][rl][j];
            }
}

// ---------- fc: [bc][16384] @ [10][16384]^T + b ----------
__global__ __launch_bounds__(256) void k_fc(const float* __restrict__ out1, const float* __restrict__ fcw,
                                            const float* __restrict__ fcb, float* __restrict__ out, int boff) {
    __shared__ float red[4][OUTW_];
    int tid = threadIdx.x;
    int bl = blockIdx.x;
    const float4* flat = (const float4*)(out1 + (size_t)bl * FCIN_);
    float pj[OUTW_];
#pragma unroll
    for (int j = 0; j < OUTW_; ++j) pj[j] = 0.f;
    for (int i = tid; i < FCIN_ / 4; i += 256) {
        float4 v = flat[i];
#pragma unroll
        for (int j = 0; j < OUTW_; ++j) {
            float4 w = ((const float4*)(fcw + (size_t)j * FCIN_))[i];
            pj[j] += v.x * w.x + v.y * w.y + v.z * w.z + v.w * w.w;
        }
    }
#pragma unroll
    for (int j = 0; j < OUTW_; ++j) {
        float v = pj[j];
        for (int off = 32; off > 0; off >>= 1) v += __shfl_xor(v, off);
        if ((tid & 63) == 0) red[tid >> 6][j] = v;
    }
    __syncthreads();
    if (tid < OUTW_) {
        float s = red[0][tid] + red[1][tid] + red[2][tid] + red[3][tid] + fcb[tid];
        out[(size_t)(boff + bl) * OUTW_ + tid] = s;
    }
}

extern "C" void kernel_launch(void* const* d_in, const int* in_sizes, int n_in,
                              void* d_out, int out_size, void* d_ws, size_t ws_size,
                              hipStream_t stream) {
    const float* x   = (const float*)d_in[0];
    const float* nw  = (const float*)d_in[1];
    const float* nb  = (const float*)d_in[2];
    const float* w1  = (const float*)d_in[3];
    const float* cb1 = (const float*)d_in[4];
    const float* w2  = (const float*)d_in[5];
    const float* cb2 = (const float*)d_in[6];
    const float* fcw = (const float*)d_in[7];
    const float* fcb = (const float*)d_in[8];
    float* out = (float*)d_out;

    float*  ws   = (float*)d_ws;
    float*  mix  = ws;                        // 2048 f
    ushort* w1fh = (ushort*)(mix + 2048);     // 16384 us
    ushort* w1fl = w1fh + 16384;              // 16384 us
    ushort* w2hl = w1fl + 16384;              // 589824 us (hi|lo interleaved per (l,icc) chunk)
    float*  out1 = (float*)(w2hl + 589824);   // Bc * 16384 f

    // fixed bytes: 2048*4 + 2*16384*2 + 589824*2 = 1253376; out1 per sample = 65536 B
    long avail = (long)ws_size - 1253376L;
    int Bc = (int)(avail / 65536L);
    if (Bc > B_) Bc = B_;
    if (Bc < 1) Bc = 1;

    k_repack_w1f<<<16384 / 256, 256, 0, stream>>>(w1, w1fh, w1fl);
    k_repack_w2<<<589824 / 256, 256, 0, stream>>>(w2, w2hl);
    k_mixture<<<B_, 256, 0, stream>>>(x, nw, nb, mix);

    for (int boff = 0; boff < B_; boff += Bc) {
        int bc = (B_ - boff < Bc) ? (B_ - boff) : Bc;
        k_fused<<<bc, 512, 0, stream>>>(x, w1fh, w1fl, cb1, w2hl, cb2, mix, out1, boff);
        k_fc<<<bc, 256, 0, stream>>>(out1, fcw, fcb, out, boff);
    }
}

// Round 13
// 166.703 us; speedup vs baseline: 1.1063x; 1.1063x over previous
//
#include <hip/hip_runtime.h>
#include <cstdint>
#include <cstddef>

#define B_ 256
#define IW_ 3072
#define L_ 8
#define NN_ 7
#define FCIN_ 16384
#define OUTW_ 10
#define ICST 40            // ushorts per (row,col) cell: 32 ic + 8 pad
#define YPLANE (324 * ICST)   // 12960 ushorts = 25920 B
#define WCHU 18432            // ushorts per (l,icc,och) W2 chunk = 36864 B = 36 KB-loads

typedef short short8 __attribute__((ext_vector_type(8)));
typedef float f32x4 __attribute__((ext_vector_type(4)));

__device__ __forceinline__ ushort f2bf(float x) {
    uint u = __float_as_uint(x);
    return (ushort)((u + 0x7fffu + ((u >> 16) & 1u)) >> 16);
}
__device__ __forceinline__ float bf2f(ushort b) { return __uint_as_float(((uint)b) << 16); }

// ---------- repack conv1 weights into MFMA frag-linear hi/lo bf16 ----------
__global__ void k_repack_w1f(const float* __restrict__ w1, ushort* __restrict__ w1fh,
                             ushort* __restrict__ w1fl) {
    int i = blockIdx.x * 256 + threadIdx.x;
    if (i >= 16384) return;
    int j    = i & 7;
    int lane = (i >> 3) & 63;
    int mt   = (i >> 9) & 3;
    int l    = i >> 11;
    int fr = lane & 15, fq = lane >> 4;
    int oc = mt * 16 + fr;
    int k = fq * 8 + j;
    float w = (k < 27) ? w1[(size_t)(l * 64 + oc) * 27 + k] : 0.f;
    ushort hb = f2bf(w);
    w1fh[i] = hb;
    w1fl[i] = f2bf(w - bf2f(hb));
}

// ---------- repack conv2 weights: [l8][icc2][och2][plane2][tap9][mt2][lane64][j8] ----------
__global__ void k_repack_w2(const float* __restrict__ w2, ushort* __restrict__ w2hl) {
    int i = blockIdx.x * 256 + threadIdx.x;
    if (i >= 589824) return;
    int j     = i & 7;
    int lane  = (i >> 3) & 63;
    int mt    = (i >> 9) & 1;
    int tap   = (i >> 10) % 9;
    int plane = (i / 9216) & 1;
    int och   = (i / 18432) & 1;
    int icc   = (i / 36864) & 1;
    int l     = i / 73728;
    int fr = lane & 15, fq = lane >> 4;
    int oc = och * 32 + mt * 16 + fr;
    int ic = icc * 32 + fq * 8 + j;
    float w = w2[(((size_t)l * 64 + oc) * 64 + ic) * 9 + tap];
    ushort hb = f2bf(w);
    w2hl[i] = plane ? f2bf(w - bf2f(hb)) : hb;
}

// ---------- mixture ----------
__global__ __launch_bounds__(256) void k_mixture(const float* __restrict__ x, const float* __restrict__ nw,
                                                 const float* __restrict__ nb, float* __restrict__ mix) {
    __shared__ float red[4 * NN_];
    __shared__ float bes[NN_];
    int b = blockIdx.x, tid = threadIdx.x;
    const float* xb = x + (size_t)b * IW_;
    float p[NN_];
#pragma unroll
    for (int n = 0; n < NN_; ++n) p[n] = 0.f;
    for (int i = tid; i < IW_; i += 256) {
        float xv = xb[i];
#pragma unroll
        for (int n = 0; n < NN_; ++n) p[n] = fmaf(xv, nw[n * IW_ + i], p[n]);
    }
#pragma unroll
    for (int n = 0; n < NN_; ++n) {
        float v = p[n];
        for (int off = 32; off > 0; off >>= 1) v += __shfl_xor(v, off);
        if ((tid & 63) == 0) red[(tid >> 6) * NN_ + n] = v;
    }
    __syncthreads();
    if (tid < NN_) {
        float s = red[tid] + red[NN_ + tid] + red[2 * NN_ + tid] + red[3 * NN_ + tid] + nb[tid];
        bes[tid] = 1.f / (1.f + expf(-s));
    }
    __syncthreads();
    if (tid < L_) {
        int leaf = tid;
        float b0 = bes[0];
        float t0 = ((leaf >> 2) & 1) ? b0 : 1.f - b0;
        float b1v = bes[1 + ((leaf >> 2) & 1)];
        float t1 = ((leaf >> 1) & 1) ? b1v : 1.f - b1v;
        float b2v = bes[3 + ((leaf >> 1) & 3)];
        float t2 = (leaf & 1) ? b2v : 1.f - b2v;
        mix[b * L_ + leaf] = t0 * t1 * t2;
    }
}

// ---------- fused conv1/conv2, oc-half blocks for 2 blocks/CU ----------
// grid = bc*2: block = (sample bl, oc-half och). 512 thr / 8 waves, 16 steps (l,icc).
// Per-wave conv2 tile: 1 mtile (16 oc) x 4 output rows -> acc+oacc = 32 regs (unified-file diet).
// W2 chunk (36 KB: this och's hi+lo) staged via global_load_lds (no VGPR round-trip, R12's
// spill source structurally eliminated). conv1 (32 MFMA) duplicated across the och pair -- the
// price of 2 blocks/CU. LDS/block = 25.9 (y) + 36 (w) = 62.8 KB; 2 blocks = 125.6 <= 160.
__global__ __launch_bounds__(512, 2) void k_fused(const float* __restrict__ x,
                                                  const ushort* __restrict__ w1fh, const ushort* __restrict__ w1fl,
                                                  const float* __restrict__ cb1,
                                                  const ushort* __restrict__ w2hl,
                                                  const float* __restrict__ cb2, const float* __restrict__ mixw,
                                                  float* __restrict__ out1, int boff) {
    __shared__ __align__(16) ushort smem[YPLANE + WCHU];   // yt 25.9 KB | wlds 36 KB = 62.8 KB
    ushort* yt = smem;
    ushort* wlds = smem + YPLANE;
    float* xpad = (float*)smem;                             // prologue-only alias (13.9 KB < yt)

    int tid = threadIdx.x;
    int bl = blockIdx.x >> 1, och = blockIdx.x & 1;
    int b = boff + bl;
    int lane = tid & 63, wid = tid >> 6;
    int fr = lane & 15, fq = lane >> 4;
    int g = wid & 1, ng = wid >> 1;               // conv2: mtile och*2+g, rows {4ng..4ng+3}

    // ---- prologue: xpad zero + fill ----
    for (int i = tid; i < 3 * 34 * 34; i += 512) xpad[i] = 0.f;
    __syncthreads();
    for (int i = tid; i < 3072; i += 512) {
        int ch = i >> 10, rr = (i >> 5) & 31, cc = i & 31;
        xpad[(ch * 34 + rr + 1) * 34 + cc + 1] = x[(size_t)b * IW_ + i];
    }
    __syncthreads();

    // ---- leaf-invariant conv1 im2col B-frags, single bf16 (RTN) ----
    short8 Bh[8];
#pragma unroll
    for (int i = 0; i < 8; ++i) {
        int nt = wid * 8 + i;
        int pos = nt * 16 + fr;          // pre-pool position, row-major 32x32
        int r = pos >> 5, c = pos & 31;
#pragma unroll
        for (int j = 0; j < 8; ++j) {
            int k = fq * 8 + j;          // k = ic*9 + tap
            float xv = 0.f;
            if (k < 27) {
                int ic = k / 9;
                int tap = k - ic * 9;
                int dr = tap / 3, dc = tap - dr * 3;
                xv = xpad[(ic * 34 + r + dr) * 34 + (c + dc)];
            }
            Bh[i][j] = (short)f2bf(xv);
        }
    }
    __syncthreads();
    {   // zero y plane (borders stay zero forever)
        uint4 z; z.x = z.y = z.z = z.w = 0u;
        for (int i = tid; i < YPLANE / 8; i += 512) ((uint4*)yt)[i] = z;
    }
    __syncthreads();

    f32x4 acc[4], oacc[4];
#pragma unroll
    for (int rl = 0; rl < 4; ++rl) { acc[rl] = (f32x4)0.f; oacc[rl] = (f32x4)0.f; }

    for (int s = 0; s < 16; ++s) {
        int l = s >> 1, icc = s & 1;

        // ---- async-stage this step's W2 chunk (36 x 1KB wave-loads) via global_load_lds ----
        {
            const char* wsrc = (const char*)(w2hl + (size_t)((l * 2 + icc) * 2 + och) * WCHU);
#pragma unroll
            for (int r = 0; r < 5; ++r) {
                int idx = r * 8 + wid;
                if (idx < 36) {
                    const char* gp = wsrc + idx * 1024 + lane * 16;
                    __builtin_amdgcn_global_load_lds(
                        (const __attribute__((address_space(1))) uint*)gp,
                        (__attribute__((address_space(3))) uint*)((char*)wlds + idx * 1024),
                        16, 0, 0);
                }
            }
        }

        // ---- conv1 phase: 32 chans (2 mtiles) of this icc chunk into y tile ----
#pragma unroll
        for (int mt2 = 0; mt2 < 2; ++mt2) {
            int mtg = icc * 2 + mt2;
            short8 ah = *(const short8*)(w1fh + ((size_t)(l * 4 + mtg) * 64 + lane) * 8);
            short8 al = *(const short8*)(w1fl + ((size_t)(l * 4 + mtg) * 64 + lane) * 8);
            f32x4 a1[8];
#pragma unroll
            for (int i = 0; i < 8; ++i) {
                f32x4 t = (f32x4)0.f;
                t = __builtin_amdgcn_mfma_f32_16x16x32_bf16(ah, Bh[i], t, 0, 0, 0);
                t = __builtin_amdgcn_mfma_f32_16x16x32_bf16(al, Bh[i], t, 0, 0, 0);
                a1[i] = t;
            }
            float4 bias4 = *(const float4*)(cb1 + l * 64 + mtg * 16 + fq * 4);
            float bb[4] = {bias4.x, bias4.y, bias4.z, bias4.w};
#pragma unroll
            for (int g4 = 0; g4 < 4; ++g4) {
                int i = (g4 & 1) + (g4 >> 1) * 4;   // {0,1,4,5}; pool partner i+2
                ushort hb[4];
#pragma unroll
                for (int j2 = 0; j2 < 4; ++j2) {
                    float m0 = fmaxf(a1[i][j2], a1[i + 2][j2]);
                    float m1 = fmaxf(m0, __shfl_xor(m0, 1));
                    float v = fmaxf(m1 + bb[j2], 0.f);
                    hb[j2] = f2bf(v);
                }
                if ((fr & 1) == 0) {
                    int pr = 2 * wid + (i >> 2);
                    int pc = ((i & 1) * 16 + fr) >> 1;
                    int off = ((pr + 1) * 18 + (pc + 1)) * ICST + mt2 * 16 + fq * 4;
                    uint2 H;
                    H.x = (uint)hb[0] | ((uint)hb[1] << 16);
                    H.y = (uint)hb[2] | ((uint)hb[3] << 16);
                    *(uint2*)&yt[off] = H;
                }
            }
        }
        __syncthreads();   // drains gll (vmcnt) + y writes visible

        // ---- conv2 phase: dc-major, A from LDS (this wave's mtile), input-row reuse ----
#pragma unroll
        for (int dc = 0; dc < 3; ++dc) {
            short8 Ah[3], Al[3];
#pragma unroll
            for (int dr = 0; dr < 3; ++dr) {
                int tap = dr * 3 + dc;
                Ah[dr] = *(const short8*)&wlds[((tap * 2 + g) * 64 + lane) * 8];
                Al[dr] = *(const short8*)&wlds[(9216 + (tap * 2 + g) * 64 + lane) * 8];
            }
#pragma unroll
            for (int rr = 0; rr < 6; ++rr) {
                int off = ((4 * ng + rr) * 18 + (fr + dc)) * ICST + fq * 8;
                short8 bh = *(const short8*)(yt + off);
#pragma unroll
                for (int dr = 0; dr < 3; ++dr) {
                    int rl = rr - dr;
                    if (rl >= 0 && rl < 4) {
                        acc[rl] = __builtin_amdgcn_mfma_f32_16x16x32_bf16(Ah[dr], bh, acc[rl], 0, 0, 0);
                        acc[rl] = __builtin_amdgcn_mfma_f32_16x16x32_bf16(Al[dr], bh, acc[rl], 0, 0, 0);
                    }
                }
            }
        }
        if (icc) {  // leaf epilogue: bias + relu + mixture accumulate
            float mx = mixw[(size_t)b * 8 + l];
#pragma unroll
            for (int j = 0; j < 4; ++j) {
                float bias = cb2[l * 64 + (och * 2 + g) * 16 + fq * 4 + j];
#pragma unroll
                for (int rl = 0; rl < 4; ++rl) {
                    float v = fmaxf(acc[rl][j] + bias, 0.f);
                    oacc[rl][j] = fmaf(mx, v, oacc[rl][j]);
                    acc[rl][j] = 0.f;
                }
            }
        }
        __syncthreads();   // protect y + wlds before next step overwrites
    }

    // ---- store out1 [bl][64 oc][256 pos] fp32 (this block fills its 32-oc half) ----
#pragma unroll
    for (int rl = 0; rl < 4; ++rl)
#pragma unroll
        for (int j = 0; j < 4; ++j) {
            int oc = (och * 2 + g) * 16 + fq * 4 + j;
            int pos = (4 * ng + rl) * 16 + fr;
            out1[((size_t)bl * 64 + oc) * 256 + pos] = oacc[rl][j];
        }
}

// ---------- fc: [bc][16384] @ [10][16384]^T + b ----------
__global__ __launch_bounds__(256) void k_fc(const float* __restrict__ out1, const float* __restrict__ fcw,
                                            const float* __restrict__ fcb, float* __restrict__ out, int boff) {
    __shared__ float red[4][OUTW_];
    int tid = threadIdx.x;
    int bl = blockIdx.x;
    const float4* flat = (const float4*)(out1 + (size_t)bl * FCIN_);
    float pj[OUTW_];
#pragma unroll
    for (int j = 0; j < OUTW_; ++j) pj[j] = 0.f;
    for (int i = tid; i < FCIN_ / 4; i += 256) {
        float4 v = flat[i];
#pragma unroll
        for (int j = 0; j < OUTW_; ++j) {
            float4 w = ((const float4*)(fcw + (size_t)j * FCIN_))[i];
            pj[j] += v.x * w.x + v.y * w.y + v.z * w.z + v.w * w.w;
        }
    }
#pragma unroll
    for (int j = 0; j < OUTW_; ++j) {
        float v = pj[j];
        for (int off = 32; off > 0; off >>= 1) v += __shfl_xor(v, off);
        if ((tid & 63) == 0) red[tid >> 6][j] = v;
    }
    __syncthreads();
    if (tid < OUTW_) {
        float s = red[0][tid] + red[1][tid] + red[2][tid] + red[3][tid] + fcb[tid];
        out[(size_t)(boff + bl) * OUTW_ + tid] = s;
    }
}

extern "C" void kernel_launch(void* const* d_in, const int* in_sizes, int n_in,
                              void* d_out, int out_size, void* d_ws, size_t ws_size,
                              hipStream_t stream) {
    const float* x   = (const float*)d_in[0];
    const float* nw  = (const float*)d_in[1];
    const float* nb  = (const float*)d_in[2];
    const float* w1  = (const float*)d_in[3];
    const float* cb1 = (const float*)d_in[4];
    const float* w2  = (const float*)d_in[5];
    const float* cb2 = (const float*)d_in[6];
    const float* fcw = (const float*)d_in[7];
    const float* fcb = (const float*)d_in[8];
    float* out = (float*)d_out;

    float*  ws   = (float*)d_ws;
    float*  mix  = ws;                        // 2048 f
    ushort* w1fh = (ushort*)(mix + 2048);     // 16384 us
    ushort* w1fl = w1fh + 16384;              // 16384 us
    ushort* w2hl = w1fl + 16384;              // 589824 us ([l][icc][och][plane][tap][mt2][lane][j8])
    float*  out1 = (float*)(w2hl + 589824);   // Bc * 16384 f

    // fixed bytes: 2048*4 + 2*16384*2 + 589824*2 = 1253376; out1 per sample = 65536 B
    long avail = (long)ws_size - 1253376L;
    int Bc = (int)(avail / 65536L);
    if (Bc > B_) Bc = B_;
    if (Bc < 1) Bc = 1;

    k_repack_w1f<<<16384 / 256, 256, 0, stream>>>(w1, w1fh, w1fl);
    k_repack_w2<<<589824 / 256, 256, 0, stream>>>(w2, w2hl);
    k_mixture<<<B_, 256, 0, stream>>>(x, nw, nb, mix);

    for (int boff = 0; boff < B_; boff += Bc) {
        int bc = (B_ - boff < Bc) ? (B_ - boff) : Bc;
        k_fused<<<bc * 2, 512, 0, stream>>>(x, w1fh, w1fl, cb1, w2hl, cb2, mix, out1, boff);
        k_fc<<<bc, 256, 0, stream>>>(out1, fcw, fcb, out, boff);
    }
}

// Round 14
// 110.468 us; speedup vs baseline: 1.6694x; 1.5091x over previous
//
#include <hip/hip_runtime.h>
#include <cstdint>
#include <cstddef>

#define B_ 256
#define IW_ 3072
#define L_ 8
#define NN_ 7
#define FCIN_ 16384
#define OUTW_ 10
#define ICST 40            // ushorts per (row,col) cell: 32 ic + 8 pad
#define YPLANE (324 * ICST)
#define WCH 36864          // ushorts per (l,icc) conv2 weight chunk: [plane2][tap9][mt4][lane64][j8]

typedef short short8 __attribute__((ext_vector_type(8)));
typedef float f32x4 __attribute__((ext_vector_type(4)));

__device__ __forceinline__ ushort f2bf(float x) {
    uint u = __float_as_uint(x);
    return (ushort)((u + 0x7fffu + ((u >> 16) & 1u)) >> 16);
}
__device__ __forceinline__ float bf2f(ushort b) { return __uint_as_float(((uint)b) << 16); }

// ---------- repack conv1 weights into MFMA frag-linear hi/lo bf16 ----------
__global__ void k_repack_w1f(const float* __restrict__ w1, ushort* __restrict__ w1fh,
                             ushort* __restrict__ w1fl) {
    int i = blockIdx.x * 256 + threadIdx.x;
    if (i >= 16384) return;
    int j    = i & 7;
    int lane = (i >> 3) & 63;
    int mt   = (i >> 9) & 3;
    int l    = i >> 11;
    int fr = lane & 15, fq = lane >> 4;
    int oc = mt * 16 + fr;
    int k = fq * 8 + j;
    float w = (k < 27) ? w1[(size_t)(l * 64 + oc) * 27 + k] : 0.f;
    ushort hb = f2bf(w);
    w1fh[i] = hb;
    w1fl[i] = f2bf(w - bf2f(hb));
}

// ---------- repack conv2 weights: single buffer [l8][icc2][plane2][tap9][mt4][lane64][j8] ----------
__global__ void k_repack_w2(const float* __restrict__ w2, ushort* __restrict__ w2hl) {
    int i = blockIdx.x * 256 + threadIdx.x;
    if (i >= 589824) return;
    int j     = i & 7;
    int lane  = (i >> 3) & 63;
    int mt    = (i >> 9) & 3;
    int tap   = (i >> 11) % 9;
    int plane = (i / 18432) & 1;
    int icc   = (i / 36864) & 1;
    int l     = i / 73728;
    int fr = lane & 15, fq = lane >> 4;
    int oc = mt * 16 + fr;
    int ic = icc * 32 + fq * 8 + j;
    float w = w2[(((size_t)l * 64 + oc) * 64 + ic) * 9 + tap];
    ushort hb = f2bf(w);
    w2hl[i] = plane ? f2bf(w - bf2f(hb)) : hb;
}

// ---------- mixture ----------
__global__ __launch_bounds__(256) void k_mixture(const float* __restrict__ x, const float* __restrict__ nw,
                                                 const float* __restrict__ nb, float* __restrict__ mix) {
    __shared__ float red[4 * NN_];
    __shared__ float bes[NN_];
    int b = blockIdx.x, tid = threadIdx.x;
    const float* xb = x + (size_t)b * IW_;
    float p[NN_];
#pragma unroll
    for (int n = 0; n < NN_; ++n) p[n] = 0.f;
    for (int i = tid; i < IW_; i += 256) {
        float xv = xb[i];
#pragma unroll
        for (int n = 0; n < NN_; ++n) p[n] = fmaf(xv, nw[n * IW_ + i], p[n]);
    }
#pragma unroll
    for (int n = 0; n < NN_; ++n) {
        float v = p[n];
        for (int off = 32; off > 0; off >>= 1) v += __shfl_xor(v, off);
        if ((tid & 63) == 0) red[(tid >> 6) * NN_ + n] = v;
    }
    __syncthreads();
    if (tid < NN_) {
        float s = red[tid] + red[NN_ + tid] + red[2 * NN_ + tid] + red[3 * NN_ + tid] + nb[tid];
        bes[tid] = 1.f / (1.f + expf(-s));
    }
    __syncthreads();
    if (tid < L_) {
        int leaf = tid;
        float b0 = bes[0];
        float t0 = ((leaf >> 2) & 1) ? b0 : 1.f - b0;
        float b1v = bes[1 + ((leaf >> 2) & 1)];
        float t1 = ((leaf >> 1) & 1) ? b1v : 1.f - b1v;
        float b2v = bes[3 + ((leaf >> 1) & 3)];
        float t2 = (leaf & 1) ? b2v : 1.f - b2v;
        mix[b * L_ + leaf] = t0 * t1 * t2;
    }
}

// ---------- fused conv1/conv2 (R11 chassis + shfl-free in-lane 2x2 pooling) ----------
// block = sample (grid 256 = 1/CU), 512 thr / 8 waves, 16 steps (8 leaves x 2 icc).
// im2col B-frag mapping puts each 2x2 pool window in ONE lane across 4 ntile slots:
//   i = {Rg(pooled-row),subrow,parity}; slot fr = pooled column. Pool = 3 same-lane fmax,
//   no shfl, no redundant lanes, all 64 lanes write uint2.
__global__ __launch_bounds__(512, 2) void k_fused(const float* __restrict__ x,
                                                  const ushort* __restrict__ w1fh, const ushort* __restrict__ w1fl,
                                                  const float* __restrict__ cb1,
                                                  const ushort* __restrict__ w2hl,
                                                  const float* __restrict__ cb2, const float* __restrict__ mixw,
                                                  float* __restrict__ out1, int boff) {
    __shared__ __align__(16) ushort smem[YPLANE + WCH];   // yt 25.9 KB | wlds 72 KB = 97.3 KB
    ushort* yt = smem;
    ushort* wlds = smem + YPLANE;
    float* xpad = (float*)smem;                            // prologue-only alias (13.9 KB < yt)

    int tid = threadIdx.x;
    int bl = blockIdx.x;
    int b = boff + bl;
    int lane = tid & 63, wid = tid >> 6;
    int fr = lane & 15, fq = lane >> 4;
    int g = wid & 1, ng = wid >> 1;               // conv2: mts {2g,2g+1}, rows {4ng..4ng+3}

    // ---- prologue: xpad zero + fill ----
    for (int i = tid; i < 3 * 34 * 34; i += 512) xpad[i] = 0.f;
    __syncthreads();
    for (int i = tid; i < 3072; i += 512) {
        int ch = i >> 10, rr = (i >> 5) & 31, cc = i & 31;
        xpad[(ch * 34 + rr + 1) * 34 + cc + 1] = x[(size_t)b * IW_ + i];
    }
    __syncthreads();

    // ---- leaf-invariant conv1 im2col B-frags (pool-window-in-lane mapping) ----
    short8 Bh[8];
#pragma unroll
    for (int i = 0; i < 8; ++i) {
        int Rg = i >> 2;                 // pooled row within wave pair
        int subrow = (i >> 1) & 1;       // pre-pool row within 2x2 window
        int parity = i & 1;              // pre-pool col parity
        int prow = (wid * 2 + Rg) * 2 + subrow;   // 0..31
        int pcol = 2 * fr + parity;               // 0..31
#pragma unroll
        for (int j = 0; j < 8; ++j) {
            int k = fq * 8 + j;          // k = ic*9 + tap
            float xv = 0.f;
            if (k < 27) {
                int ic = k / 9;
                int tap = k - ic * 9;
                int dr = tap / 3, dc = tap - dr * 3;
                xv = xpad[(ic * 34 + prow + dr) * 34 + (pcol + dc)];
            }
            Bh[i][j] = (short)f2bf(xv);
        }
    }
    __syncthreads();
    {   // zero y plane (borders stay zero forever)
        uint4 z; z.x = z.y = z.z = z.w = 0u;
        for (int i = tid; i < YPLANE / 8; i += 512) ((uint4*)yt)[i] = z;
    }
    __syncthreads();

    f32x4 acc[2][4], oacc[2][4];
#pragma unroll
    for (int m = 0; m < 2; ++m)
#pragma unroll
        for (int rl = 0; rl < 4; ++rl) { acc[m][rl] = (f32x4)0.f; oacc[m][rl] = (f32x4)0.f; }

    for (int s = 0; s < 16; ++s) {
        int l = s >> 1, icc = s & 1;

        // ---- issue this step's W2 chunk loads EARLY (latency hides under conv1) ----
        uint4 stg[9];
        {
            const uint4* wsrc = (const uint4*)(w2hl + (size_t)(l * 2 + icc) * WCH);
#pragma unroll
            for (int r = 0; r < 9; ++r) stg[r] = wsrc[r * 512 + tid];
        }

        // ---- conv1 phase: 32 chans (2 mtiles), in-lane pool, all lanes write ----
#pragma unroll
        for (int mt2 = 0; mt2 < 2; ++mt2) {
            int mtg = icc * 2 + mt2;
            short8 ah = *(const short8*)(w1fh + ((size_t)(l * 4 + mtg) * 64 + lane) * 8);
            short8 al = *(const short8*)(w1fl + ((size_t)(l * 4 + mtg) * 64 + lane) * 8);
            f32x4 a1[8];
#pragma unroll
            for (int i = 0; i < 8; ++i) {
                f32x4 t = (f32x4)0.f;
                t = __builtin_amdgcn_mfma_f32_16x16x32_bf16(ah, Bh[i], t, 0, 0, 0);
                t = __builtin_amdgcn_mfma_f32_16x16x32_bf16(al, Bh[i], t, 0, 0, 0);
                a1[i] = t;
            }
            float4 bias4 = *(const float4*)(cb1 + l * 64 + mtg * 16 + fq * 4);
            float bb[4] = {bias4.x, bias4.y, bias4.z, bias4.w};
#pragma unroll
            for (int Rg = 0; Rg < 2; ++Rg) {
                ushort hb[4];
#pragma unroll
                for (int j2 = 0; j2 < 4; ++j2) {
                    float m0 = fmaxf(fmaxf(a1[Rg * 4 + 0][j2], a1[Rg * 4 + 1][j2]),
                                     fmaxf(a1[Rg * 4 + 2][j2], a1[Rg * 4 + 3][j2]));
                    float v = fmaxf(m0 + bb[j2], 0.f);
                    hb[j2] = f2bf(v);
                }
                int pr = 2 * wid + Rg;
                int off = ((pr + 1) * 18 + (fr + 1)) * ICST + mt2 * 16 + fq * 4;
                uint2 H;
                H.x = (uint)hb[0] | ((uint)hb[1] << 16);
                H.y = (uint)hb[2] | ((uint)hb[3] << 16);
                *(uint2*)&yt[off] = H;
            }
        }

        // ---- write staged W2 chunk to LDS (vmcnt auto-waits), then publish ----
#pragma unroll
        for (int r = 0; r < 9; ++r) *(uint4*)&wlds[(r * 512 + tid) * 8] = stg[r];
        __syncthreads();

        // ---- conv2 phase: dc-major, A from LDS, input-row reuse across row-taps ----
#pragma unroll
        for (int dc = 0; dc < 3; ++dc) {
            short8 Ah[2][3], Al[2][3];
#pragma unroll
            for (int dr = 0; dr < 3; ++dr) {
                int tap = dr * 3 + dc;
#pragma unroll
                for (int m = 0; m < 2; ++m) {
                    int mt = 2 * g + m;
                    Ah[m][dr] = *(const short8*)&wlds[((tap * 4 + mt) * 64 + lane) * 8];
                    Al[m][dr] = *(const short8*)&wlds[(((9 + tap) * 4 + mt) * 64 + lane) * 8];
                }
            }
#pragma unroll
            for (int rr = 0; rr < 6; ++rr) {
                int off = ((4 * ng + rr) * 18 + (fr + dc)) * ICST + fq * 8;
                short8 bh = *(const short8*)(yt + off);
#pragma unroll
                for (int dr = 0; dr < 3; ++dr) {
                    int rl = rr - dr;
                    if (rl >= 0 && rl < 4) {
#pragma unroll
                        for (int m = 0; m < 2; ++m) {
                            acc[m][rl] = __builtin_amdgcn_mfma_f32_16x16x32_bf16(Ah[m][dr], bh, acc[m][rl], 0, 0, 0);
                            acc[m][rl] = __builtin_amdgcn_mfma_f32_16x16x32_bf16(Al[m][dr], bh, acc[m][rl], 0, 0, 0);
                        }
                    }
                }
            }
        }
        if (icc) {  // leaf epilogue: bias + relu + mixture accumulate
            float mx = mixw[(size_t)b * 8 + l];
#pragma unroll
            for (int m = 0; m < 2; ++m)
#pragma unroll
                for (int j = 0; j < 4; ++j) {
                    float bias = cb2[l * 64 + (2 * g + m) * 16 + fq * 4 + j];
#pragma unroll
                    for (int rl = 0; rl < 4; ++rl) {
                        float v = fmaxf(acc[m][rl][j] + bias, 0.f);
                        oacc[m][rl][j] = fmaf(mx, v, oacc[m][rl][j]);
                        acc[m][rl][j] = 0.f;
                    }
                }
        }
        __syncthreads();
    }

    // ---- store out1 [bl][64 oc][256 pos] fp32 ----
#pragma unroll
    for (int m = 0; m < 2; ++m)
#pragma unroll
        for (int rl = 0; rl < 4; ++rl)
#pragma unroll
            for (int j = 0; j < 4; ++j) {
                int oc = (2 * g + m) * 16 + fq * 4 + j;
                int pos = (4 * ng + rl) * 16 + fr;
                out1[((size_t)bl * 64 + oc) * 256 + pos] = oacc[m][rl][j];
            }
}

// ---------- fc: [bc][16384] @ [10][16384]^T + b ----------
__global__ __launch_bounds__(256) void k_fc(const float* __restrict__ out1, const float* __restrict__ fcw,
                                            const float* __restrict__ fcb, float* __restrict__ out, int boff) {
    __shared__ float red[4][OUTW_];
    int tid = threadIdx.x;
    int bl = blockIdx.x;
    const float4* flat = (const float4*)(out1 + (size_t)bl * FCIN_);
    float pj[OUTW_];
#pragma unroll
    for (int j = 0; j < OUTW_; ++j) pj[j] = 0.f;
    for (int i = tid; i < FCIN_ / 4; i += 256) {
        float4 v = flat[i];
#pragma unroll
        for (int j = 0; j < OUTW_; ++j) {
            float4 w = ((const float4*)(fcw + (size_t)j * FCIN_))[i];
            pj[j] += v.x * w.x + v.y * w.y + v.z * w.z + v.w * w.w;
        }
    }
#pragma unroll
    for (int j = 0; j < OUTW_; ++j) {
        float v = pj[j];
        for (int off = 32; off > 0; off >>= 1) v += __shfl_xor(v, off);
        if ((tid & 63) == 0) red[tid >> 6][j] = v;
    }
    __syncthreads();
    if (tid < OUTW_) {
        float s = red[0][tid] + red[1][tid] + red[2][tid] + red[3][tid] + fcb[tid];
        out[(size_t)(boff + bl) * OUTW_ + tid] = s;
    }
}

extern "C" void kernel_launch(void* const* d_in, const int* in_sizes, int n_in,
                              void* d_out, int out_size, void* d_ws, size_t ws_size,
                              hipStream_t stream) {
    const float* x   = (const float*)d_in[0];
    const float* nw  = (const float*)d_in[1];
    const float* nb  = (const float*)d_in[2];
    const float* w1  = (const float*)d_in[3];
    const float* cb1 = (const float*)d_in[4];
    const float* w2  = (const float*)d_in[5];
    const float* cb2 = (const float*)d_in[6];
    const float* fcw = (const float*)d_in[7];
    const float* fcb = (const float*)d_in[8];
    float* out = (float*)d_out;

    float*  ws   = (float*)d_ws;
    float*  mix  = ws;                        // 2048 f
    ushort* w1fh = (ushort*)(mix + 2048);     // 16384 us
    ushort* w1fl = w1fh + 16384;              // 16384 us
    ushort* w2hl = w1fl + 16384;              // 589824 us (hi|lo interleaved per (l,icc) chunk)
    float*  out1 = (float*)(w2hl + 589824);   // Bc * 16384 f

    // fixed bytes: 2048*4 + 2*16384*2 + 589824*2 = 1253376; out1 per sample = 65536 B
    long avail = (long)ws_size - 1253376L;
    int Bc = (int)(avail / 65536L);
    if (Bc > B_) Bc = B_;
    if (Bc < 1) Bc = 1;

    k_repack_w1f<<<16384 / 256, 256, 0, stream>>>(w1, w1fh, w1fl);
    k_repack_w2<<<589824 / 256, 256, 0, stream>>>(w2, w2hl);
    k_mixture<<<B_, 256, 0, stream>>>(x, nw, nb, mix);

    for (int boff = 0; boff < B_; boff += Bc) {
        int bc = (B_ - boff < Bc) ? (B_ - boff) : Bc;
        k_fused<<<bc, 512, 0, stream>>>(x, w1fh, w1fl, cb1, w2hl, cb2, mix, out1, boff);
        k_fc<<<bc, 256, 0, stream>>>(out1, fcw, fcb, out, boff);
    }
}

// Round 15
// 102.210 us; speedup vs baseline: 1.8043x; 1.0808x over previous
//
#include <hip/hip_runtime.h>
#include <cstdint>
#include <cstddef>

#define B_ 256
#define IW_ 3072
#define L_ 8
#define NN_ 7
#define FCIN_ 16384
#define OUTW_ 10
#define ICST 40            // ushorts per (row,col) cell: 32 ic + 8 pad
#define YPLANE (324 * ICST)
#define WCH 36864          // ushorts per (l,icc) conv2 weight chunk: [plane2][tap9][mt4][lane64][j8]

typedef short short8 __attribute__((ext_vector_type(8)));
typedef float f32x4 __attribute__((ext_vector_type(4)));

__device__ __forceinline__ ushort f2bf(float x) {
    uint u = __float_as_uint(x);
    return (ushort)((u + 0x7fffu + ((u >> 16) & 1u)) >> 16);
}
__device__ __forceinline__ float bf2f(ushort b) { return __uint_as_float(((uint)b) << 16); }

// ---------- merged prep: [0,64) w1f repack | [64,2368) w2 repack | [2368,2624) mixture ----------
__global__ __launch_bounds__(256) void k_prep(const float* __restrict__ w1, ushort* __restrict__ w1fh,
                                              ushort* __restrict__ w1fl,
                                              const float* __restrict__ w2, ushort* __restrict__ w2hl,
                                              const float* __restrict__ x, const float* __restrict__ nw,
                                              const float* __restrict__ nb, float* __restrict__ mix) {
    int blk = blockIdx.x;
    if (blk < 64) {
        // conv1 weights -> frag-linear hi/lo: [l8][mt4][lane64][j8]
        int i = blk * 256 + threadIdx.x;
        int j    = i & 7;
        int lane = (i >> 3) & 63;
        int mt   = (i >> 9) & 3;
        int l    = i >> 11;
        int fr = lane & 15, fq = lane >> 4;
        int oc = mt * 16 + fr;
        int k = fq * 8 + j;
        float w = (k < 27) ? w1[(size_t)(l * 64 + oc) * 27 + k] : 0.f;
        ushort hb = f2bf(w);
        w1fh[i] = hb;
        w1fl[i] = f2bf(w - bf2f(hb));
        return;
    }
    if (blk < 2368) {
        // conv2 weights -> [l8][icc2][plane2][tap9][mt4][lane64][j8]
        int i = (blk - 64) * 256 + threadIdx.x;
        int j     = i & 7;
        int lane  = (i >> 3) & 63;
        int mt    = (i >> 9) & 3;
        int tap   = (i >> 11) % 9;
        int plane = (i / 18432) & 1;
        int icc   = (i / 36864) & 1;
        int l     = i / 73728;
        int fr = lane & 15, fq = lane >> 4;
        int oc = mt * 16 + fr;
        int ic = icc * 32 + fq * 8 + j;
        float w = w2[(((size_t)l * 64 + oc) * 64 + ic) * 9 + tap];
        ushort hb = f2bf(w);
        w2hl[i] = plane ? f2bf(w - bf2f(hb)) : hb;
        return;
    }
    // mixture
    __shared__ float red[4 * NN_];
    __shared__ float bes[NN_];
    int b = blk - 2368, tid = threadIdx.x;
    const float* xb = x + (size_t)b * IW_;
    float p[NN_];
#pragma unroll
    for (int n = 0; n < NN_; ++n) p[n] = 0.f;
    for (int i = tid; i < IW_; i += 256) {
        float xv = xb[i];
#pragma unroll
        for (int n = 0; n < NN_; ++n) p[n] = fmaf(xv, nw[n * IW_ + i], p[n]);
    }
#pragma unroll
    for (int n = 0; n < NN_; ++n) {
        float v = p[n];
        for (int off = 32; off > 0; off >>= 1) v += __shfl_xor(v, off);
        if ((tid & 63) == 0) red[(tid >> 6) * NN_ + n] = v;
    }
    __syncthreads();
    if (tid < NN_) {
        float s = red[tid] + red[NN_ + tid] + red[2 * NN_ + tid] + red[3 * NN_ + tid] + nb[tid];
        bes[tid] = 1.f / (1.f + expf(-s));
    }
    __syncthreads();
    if (tid < L_) {
        int leaf = tid;
        float b0 = bes[0];
        float t0 = ((leaf >> 2) & 1) ? b0 : 1.f - b0;
        float b1v = bes[1 + ((leaf >> 2) & 1)];
        float t1 = ((leaf >> 1) & 1) ? b1v : 1.f - b1v;
        float b2v = bes[3 + ((leaf >> 1) & 3)];
        float t2 = (leaf & 1) ? b2v : 1.f - b2v;
        mix[b * L_ + leaf] = t0 * t1 * t2;
    }
}

// ---------- fused conv1/conv2 (R14 chassis + global_load_lds W2 staging) ----------
// block = sample (grid 256 = 1/CU), 512 thr / 8 waves, 16 steps (8 leaves x 2 icc).
// Step: issue 9 gll (72KB W2 chunk, DMA global->LDS, hides under conv1) -> conv1 MFMA +
// in-lane 2x2 pool (no shfl) -> barrier (drains vmcnt: wlds ready, y visible) -> conv2
// dc-major MFMA (A + y from LDS) -> epilogue -> barrier (protect LDS for next step).
__global__ __launch_bounds__(512, 2) void k_fused(const float* __restrict__ x,
                                                  const ushort* __restrict__ w1fh, const ushort* __restrict__ w1fl,
                                                  const float* __restrict__ cb1,
                                                  const ushort* __restrict__ w2hl,
                                                  const float* __restrict__ cb2, const float* __restrict__ mixw,
                                                  float* __restrict__ out1, int boff) {
    __shared__ __align__(16) ushort smem[YPLANE + WCH];   // yt 25.9 KB | wlds 72 KB = 97.3 KB
    ushort* yt = smem;
    ushort* wlds = smem + YPLANE;
    float* xpad = (float*)smem;                            // prologue-only alias (13.9 KB < yt)

    int tid = threadIdx.x;
    int bl = blockIdx.x;
    int b = boff + bl;
    int lane = tid & 63, wid = tid >> 6;
    int fr = lane & 15, fq = lane >> 4;
    int g = wid & 1, ng = wid >> 1;               // conv2: mts {2g,2g+1}, rows {4ng..4ng+3}

    // ---- prologue: xpad zero + fill ----
    for (int i = tid; i < 3 * 34 * 34; i += 512) xpad[i] = 0.f;
    __syncthreads();
    for (int i = tid; i < 3072; i += 512) {
        int ch = i >> 10, rr = (i >> 5) & 31, cc = i & 31;
        xpad[(ch * 34 + rr + 1) * 34 + cc + 1] = x[(size_t)b * IW_ + i];
    }
    __syncthreads();

    // ---- leaf-invariant conv1 im2col B-frags (pool-window-in-lane mapping) ----
    short8 Bh[8];
#pragma unroll
    for (int i = 0; i < 8; ++i) {
        int Rg = i >> 2;                 // pooled row within wave pair
        int subrow = (i >> 1) & 1;       // pre-pool row within 2x2 window
        int parity = i & 1;              // pre-pool col parity
        int prow = (wid * 2 + Rg) * 2 + subrow;   // 0..31
        int pcol = 2 * fr + parity;               // 0..31
#pragma unroll
        for (int j = 0; j < 8; ++j) {
            int k = fq * 8 + j;          // k = ic*9 + tap
            float xv = 0.f;
            if (k < 27) {
                int ic = k / 9;
                int tap = k - ic * 9;
                int dr = tap / 3, dc = tap - dr * 3;
                xv = xpad[(ic * 34 + prow + dr) * 34 + (pcol + dc)];
            }
            Bh[i][j] = (short)f2bf(xv);
        }
    }
    __syncthreads();
    {   // zero y plane (borders stay zero forever)
        uint4 z; z.x = z.y = z.z = z.w = 0u;
        for (int i = tid; i < YPLANE / 8; i += 512) ((uint4*)yt)[i] = z;
    }
    __syncthreads();

    f32x4 acc[2][4], oacc[2][4];
#pragma unroll
    for (int m = 0; m < 2; ++m)
#pragma unroll
        for (int rl = 0; rl < 4; ++rl) { acc[m][rl] = (f32x4)0.f; oacc[m][rl] = (f32x4)0.f; }

    for (int s = 0; s < 16; ++s) {
        int l = s >> 1, icc = s & 1;

        // ---- async-stage this step's 72KB W2 chunk via global_load_lds (hides under conv1) ----
        {
            const char* wsrc = (const char*)(w2hl + (size_t)(l * 2 + icc) * WCH);
#pragma unroll
            for (int r = 0; r < 9; ++r) {
                int idx = r * 8 + wid;                 // 0..71 wave-loads of 1KB
                const char* gp = wsrc + idx * 1024 + lane * 16;
                __builtin_amdgcn_global_load_lds(
                    (const __attribute__((address_space(1))) uint*)gp,
                    (__attribute__((address_space(3))) uint*)((char*)wlds + idx * 1024),
                    16, 0, 0);
            }
        }

        // ---- conv1 phase: 32 chans (2 mtiles), in-lane pool, all lanes write ----
#pragma unroll
        for (int mt2 = 0; mt2 < 2; ++mt2) {
            int mtg = icc * 2 + mt2;
            short8 ah = *(const short8*)(w1fh + ((size_t)(l * 4 + mtg) * 64 + lane) * 8);
            short8 al = *(const short8*)(w1fl + ((size_t)(l * 4 + mtg) * 64 + lane) * 8);
            f32x4 a1[8];
#pragma unroll
            for (int i = 0; i < 8; ++i) {
                f32x4 t = (f32x4)0.f;
                t = __builtin_amdgcn_mfma_f32_16x16x32_bf16(ah, Bh[i], t, 0, 0, 0);
                t = __builtin_amdgcn_mfma_f32_16x16x32_bf16(al, Bh[i], t, 0, 0, 0);
                a1[i] = t;
            }
            float4 bias4 = *(const float4*)(cb1 + l * 64 + mtg * 16 + fq * 4);
            float bb[4] = {bias4.x, bias4.y, bias4.z, bias4.w};
#pragma unroll
            for (int Rg = 0; Rg < 2; ++Rg) {
                ushort hb[4];
#pragma unroll
                for (int j2 = 0; j2 < 4; ++j2) {
                    float m0 = fmaxf(fmaxf(a1[Rg * 4 + 0][j2], a1[Rg * 4 + 1][j2]),
                                     fmaxf(a1[Rg * 4 + 2][j2], a1[Rg * 4 + 3][j2]));
                    float v = fmaxf(m0 + bb[j2], 0.f);
                    hb[j2] = f2bf(v);
                }
                int pr = 2 * wid + Rg;
                int off = ((pr + 1) * 18 + (fr + 1)) * ICST + mt2 * 16 + fq * 4;
                uint2 H;
                H.x = (uint)hb[0] | ((uint)hb[1] << 16);
                H.y = (uint)hb[2] | ((uint)hb[3] << 16);
                *(uint2*)&yt[off] = H;
            }
        }
        __syncthreads();   // drains vmcnt (gll complete) + y writes visible

        // ---- conv2 phase: dc-major, A from LDS, input-row reuse across row-taps ----
#pragma unroll
        for (int dc = 0; dc < 3; ++dc) {
            short8 Ah[2][3], Al[2][3];
#pragma unroll
            for (int dr = 0; dr < 3; ++dr) {
                int tap = dr * 3 + dc;
#pragma unroll
                for (int m = 0; m < 2; ++m) {
                    int mt = 2 * g + m;
                    Ah[m][dr] = *(const short8*)&wlds[((tap * 4 + mt) * 64 + lane) * 8];
                    Al[m][dr] = *(const short8*)&wlds[(((9 + tap) * 4 + mt) * 64 + lane) * 8];
                }
            }
#pragma unroll
            for (int rr = 0; rr < 6; ++rr) {
                int off = ((4 * ng + rr) * 18 + (fr + dc)) * ICST + fq * 8;
                short8 bh = *(const short8*)(yt + off);
#pragma unroll
                for (int dr = 0; dr < 3; ++dr) {
                    int rl = rr - dr;
                    if (rl >= 0 && rl < 4) {
#pragma unroll
                        for (int m = 0; m < 2; ++m) {
                            acc[m][rl] = __builtin_amdgcn_mfma_f32_16x16x32_bf16(Ah[m][dr], bh, acc[m][rl], 0, 0, 0);
                            acc[m][rl] = __builtin_amdgcn_mfma_f32_16x16x32_bf16(Al[m][dr], bh, acc[m][rl], 0, 0, 0);
                        }
                    }
                }
            }
        }
        if (icc) {  // leaf epilogue: bias + relu + mixture accumulate
            float mx = mixw[(size_t)b * 8 + l];
#pragma unroll
            for (int m = 0; m < 2; ++m)
#pragma unroll
                for (int j = 0; j < 4; ++j) {
                    float bias = cb2[l * 64 + (2 * g + m) * 16 + fq * 4 + j];
#pragma unroll
                    for (int rl = 0; rl < 4; ++rl) {
                        float v = fmaxf(acc[m][rl][j] + bias, 0.f);
                        oacc[m][rl][j] = fmaf(mx, v, oacc[m][rl][j]);
                        acc[m][rl][j] = 0.f;
                    }
                }
        }
        __syncthreads();   // protect y + wlds before next step's gll/writes
    }

    // ---- store out1 [bl][64 oc][256 pos] fp32 ----
#pragma unroll
    for (int m = 0; m < 2; ++m)
#pragma unroll
        for (int rl = 0; rl < 4; ++rl)
#pragma unroll
            for (int j = 0; j < 4; ++j) {
                int oc = (2 * g + m) * 16 + fq * 4 + j;
                int pos = (4 * ng + rl) * 16 + fr;
                out1[((size_t)bl * 64 + oc) * 256 + pos] = oacc[m][rl][j];
            }
}

// ---------- fc: [bc][16384] @ [10][16384]^T + b ----------
__global__ __launch_bounds__(256) void k_fc(const float* __restrict__ out1, const float* __restrict__ fcw,
                                            const float* __restrict__ fcb, float* __restrict__ out, int boff) {
    __shared__ float red[4][OUTW_];
    int tid = threadIdx.x;
    int bl = blockIdx.x;
    const float4* flat = (const float4*)(out1 + (size_t)bl * FCIN_);
    float pj[OUTW_];
#pragma unroll
    for (int j = 0; j < OUTW_; ++j) pj[j] = 0.f;
    for (int i = tid; i < FCIN_ / 4; i += 256) {
        float4 v = flat[i];
#pragma unroll
        for (int j = 0; j < OUTW_; ++j) {
            float4 w = ((const float4*)(fcw + (size_t)j * FCIN_))[i];
            pj[j] += v.x * w.x + v.y * w.y + v.z * w.z + v.w * w.w;
        }
    }
#pragma unroll
    for (int j = 0; j < OUTW_; ++j) {
        float v = pj[j];
        for (int off = 32; off > 0; off >>= 1) v += __shfl_xor(v, off);
        if ((tid & 63) == 0) red[tid >> 6][j] = v;
    }
    __syncthreads();
    if (tid < OUTW_) {
        float s = red[0][tid] + red[1][tid] + red[2][tid] + red[3][tid] + fcb[tid];
        out[(size_t)(boff + bl) * OUTW_ + tid] = s;
    }
}

extern "C" void kernel_launch(void* const* d_in, const int* in_sizes, int n_in,
                              void* d_out, int out_size, void* d_ws, size_t ws_size,
                              hipStream_t stream) {
    const float* x   = (const float*)d_in[0];
    const float* nw  = (const float*)d_in[1];
    const float* nb  = (const float*)d_in[2];
    const float* w1  = (const float*)d_in[3];
    const float* cb1 = (const float*)d_in[4];
    const float* w2  = (const float*)d_in[5];
    const float* cb2 = (const float*)d_in[6];
    const float* fcw = (const float*)d_in[7];
    const float* fcb = (const float*)d_in[8];
    float* out = (float*)d_out;

    float*  ws   = (float*)d_ws;
    float*  mix  = ws;                        // 2048 f
    ushort* w1fh = (ushort*)(mix + 2048);     // 16384 us
    ushort* w1fl = w1fh + 16384;              // 16384 us
    ushort* w2hl = w1fl + 16384;              // 589824 us (hi|lo interleaved per (l,icc) chunk)
    float*  out1 = (float*)(w2hl + 589824);   // Bc * 16384 f

    // fixed bytes: 2048*4 + 2*16384*2 + 589824*2 = 1253376; out1 per sample = 65536 B
    long avail = (long)ws_size - 1253376L;
    int Bc = (int)(avail / 65536L);
    if (Bc > B_) Bc = B_;
    if (Bc < 1) Bc = 1;

    k_prep<<<2624, 256, 0, stream>>>(w1, w1fh, w1fl, w2, w2hl, x, nw, nb, mix);

    for (int boff = 0; boff < B_; boff += Bc) {
        int bc = (B_ - boff < Bc) ? (B_ - boff) : Bc;
        k_fused<<<bc, 512, 0, stream>>>(x, w1fh, w1fl, cb1, w2hl, cb2, mix, out1, boff);
        k_fc<<<bc, 256, 0, stream>>>(out1, fcw, fcb, out, boff);
    }
}

// Round 16
// 82.575 us; speedup vs baseline: 2.2334x; 1.2378x over previous
//
#include <hip/hip_runtime.h>
#include <cstdint>
#include <cstddef>

#define B_ 256
#define IW_ 3072
#define L_ 8
#define NN_ 7
#define FCIN_ 16384
#define OUTW_ 10
#define ICST 40            // ushorts per (row,col) cell: 32 ic + 8 pad
#define YPLANE (324 * ICST)
#define WCH 18432          // ushorts per (l,icc) conv2 weight chunk: [tap9][mt4][lane64][j8] single RTN plane

typedef short short8 __attribute__((ext_vector_type(8)));
typedef float f32x4 __attribute__((ext_vector_type(4)));

__device__ __forceinline__ ushort f2bf(float x) {
    uint u = __float_as_uint(x);
    return (ushort)((u + 0x7fffu + ((u >> 16) & 1u)) >> 16);
}
__device__ __forceinline__ float bf2f(ushort b) { return __uint_as_float(((uint)b) << 16); }

// ---------- merged prep: [0,64) w1f repack | [64,1216) w2 repack | [1216,1472) mixture ----------
__global__ __launch_bounds__(256) void k_prep(const float* __restrict__ w1, ushort* __restrict__ w1fh,
                                              ushort* __restrict__ w1fl,
                                              const float* __restrict__ w2, ushort* __restrict__ w2r,
                                              const float* __restrict__ x, const float* __restrict__ nw,
                                              const float* __restrict__ nb, float* __restrict__ mix) {
    int blk = blockIdx.x;
    if (blk < 64) {
        // conv1 weights -> frag-linear hi/lo: [l8][mt4][lane64][j8] (exact 2-plane split)
        int i = blk * 256 + threadIdx.x;
        int j    = i & 7;
        int lane = (i >> 3) & 63;
        int mt   = (i >> 9) & 3;
        int l    = i >> 11;
        int fr = lane & 15, fq = lane >> 4;
        int oc = mt * 16 + fr;
        int k = fq * 8 + j;
        float w = (k < 27) ? w1[(size_t)(l * 64 + oc) * 27 + k] : 0.f;
        ushort hb = f2bf(w);
        w1fh[i] = hb;
        w1fl[i] = f2bf(w - bf2f(hb));
        return;
    }
    if (blk < 1216) {
        // conv2 weights -> [l8][icc2][tap9][mt4][lane64][j8], single RTN bf16 plane
        int i = (blk - 64) * 256 + threadIdx.x;
        int j     = i & 7;
        int lane  = (i >> 3) & 63;
        int mt    = (i >> 9) & 3;
        int tap   = (i >> 11) % 9;
        int icc   = (i / 18432) & 1;
        int l     = i / 36864;
        int fr = lane & 15, fq = lane >> 4;
        int oc = mt * 16 + fr;
        int ic = icc * 32 + fq * 8 + j;
        float w = w2[(((size_t)l * 64 + oc) * 64 + ic) * 9 + tap];
        w2r[i] = f2bf(w);
        return;
    }
    // mixture
    __shared__ float red[4 * NN_];
    __shared__ float bes[NN_];
    int b = blk - 1216, tid = threadIdx.x;
    const float* xb = x + (size_t)b * IW_;
    float p[NN_];
#pragma unroll
    for (int n = 0; n < NN_; ++n) p[n] = 0.f;
    for (int i = tid; i < IW_; i += 256) {
        float xv = xb[i];
#pragma unroll
        for (int n = 0; n < NN_; ++n) p[n] = fmaf(xv, nw[n * IW_ + i], p[n]);
    }
#pragma unroll
    for (int n = 0; n < NN_; ++n) {
        float v = p[n];
        for (int off = 32; off > 0; off >>= 1) v += __shfl_xor(v, off);
        if ((tid & 63) == 0) red[(tid >> 6) * NN_ + n] = v;
    }
    __syncthreads();
    if (tid < NN_) {
        float s = red[tid] + red[NN_ + tid] + red[2 * NN_ + tid] + red[3 * NN_ + tid] + nb[tid];
        bes[tid] = 1.f / (1.f + expf(-s));
    }
    __syncthreads();
    if (tid < L_) {
        int leaf = tid;
        float b0 = bes[0];
        float t0 = ((leaf >> 2) & 1) ? b0 : 1.f - b0;
        float b1v = bes[1 + ((leaf >> 2) & 1)];
        float t1 = ((leaf >> 1) & 1) ? b1v : 1.f - b1v;
        float b2v = bes[3 + ((leaf >> 1) & 3)];
        float t2 = (leaf & 1) ? b2v : 1.f - b2v;
        mix[b * L_ + leaf] = t0 * t1 * t2;
    }
}

// ---------- fused conv1/conv2 (R15 chassis, conv2 single-plane W) ----------
// block = sample (grid 256 = 1/CU), 512 thr / 8 waves, 16 steps (8 leaves x 2 icc).
// Step: issue gll (36KB single-plane W2 chunk, DMA global->LDS, hides under conv1) ->
// conv1 MFMA (exact hi/lo W1 x RTN-bf16 im2col) + in-lane 2x2 pool -> barrier ->
// conv2 dc-major MFMA, ONE product per tap (W RTN x y RTN; error ~sqrt(2) x y-only) ->
// epilogue -> barrier.
__global__ __launch_bounds__(512, 2) void k_fused(const float* __restrict__ x,
                                                  const ushort* __restrict__ w1fh, const ushort* __restrict__ w1fl,
                                                  const float* __restrict__ cb1,
                                                  const ushort* __restrict__ w2r,
                                                  const float* __restrict__ cb2, const float* __restrict__ mixw,
                                                  float* __restrict__ out1, int boff) {
    __shared__ __align__(16) ushort smem[YPLANE + WCH];   // yt 25.9 KB | wlds 36 KB = 62.8 KB
    ushort* yt = smem;
    ushort* wlds = smem + YPLANE;
    float* xpad = (float*)smem;                            // prologue-only alias (13.9 KB < yt)

    int tid = threadIdx.x;
    int bl = blockIdx.x;
    int b = boff + bl;
    int lane = tid & 63, wid = tid >> 6;
    int fr = lane & 15, fq = lane >> 4;
    int g = wid & 1, ng = wid >> 1;               // conv2: mts {2g,2g+1}, rows {4ng..4ng+3}

    // ---- prologue: xpad zero + fill ----
    for (int i = tid; i < 3 * 34 * 34; i += 512) xpad[i] = 0.f;
    __syncthreads();
    for (int i = tid; i < 3072; i += 512) {
        int ch = i >> 10, rr = (i >> 5) & 31, cc = i & 31;
        xpad[(ch * 34 + rr + 1) * 34 + cc + 1] = x[(size_t)b * IW_ + i];
    }
    __syncthreads();

    // ---- leaf-invariant conv1 im2col B-frags (pool-window-in-lane mapping) ----
    short8 Bh[8];
#pragma unroll
    for (int i = 0; i < 8; ++i) {
        int Rg = i >> 2;                 // pooled row within wave pair
        int subrow = (i >> 1) & 1;       // pre-pool row within 2x2 window
        int parity = i & 1;              // pre-pool col parity
        int prow = (wid * 2 + Rg) * 2 + subrow;   // 0..31
        int pcol = 2 * fr + parity;               // 0..31
#pragma unroll
        for (int j = 0; j < 8; ++j) {
            int k = fq * 8 + j;          // k = ic*9 + tap
            float xv = 0.f;
            if (k < 27) {
                int ic = k / 9;
                int tap = k - ic * 9;
                int dr = tap / 3, dc = tap - dr * 3;
                xv = xpad[(ic * 34 + prow + dr) * 34 + (pcol + dc)];
            }
            Bh[i][j] = (short)f2bf(xv);
        }
    }
    __syncthreads();
    {   // zero y plane (borders stay zero forever)
        uint4 z; z.x = z.y = z.z = z.w = 0u;
        for (int i = tid; i < YPLANE / 8; i += 512) ((uint4*)yt)[i] = z;
    }
    __syncthreads();

    f32x4 acc[2][4], oacc[2][4];
#pragma unroll
    for (int m = 0; m < 2; ++m)
#pragma unroll
        for (int rl = 0; rl < 4; ++rl) { acc[m][rl] = (f32x4)0.f; oacc[m][rl] = (f32x4)0.f; }

    for (int s = 0; s < 16; ++s) {
        int l = s >> 1, icc = s & 1;

        // ---- async-stage this step's 36KB W2 chunk via global_load_lds (hides under conv1) ----
        {
            const char* wsrc = (const char*)(w2r + (size_t)(l * 2 + icc) * WCH);
#pragma unroll
            for (int r = 0; r < 5; ++r) {
                int idx = r * 8 + wid;                 // 0..39, guard to 36 (wave-uniform)
                if (idx < 36) {
                    const char* gp = wsrc + idx * 1024 + lane * 16;
                    __builtin_amdgcn_global_load_lds(
                        (const __attribute__((address_space(1))) uint*)gp,
                        (__attribute__((address_space(3))) uint*)((char*)wlds + idx * 1024),
                        16, 0, 0);
                }
            }
        }

        // ---- conv1 phase: 32 chans (2 mtiles), in-lane pool, all lanes write ----
#pragma unroll
        for (int mt2 = 0; mt2 < 2; ++mt2) {
            int mtg = icc * 2 + mt2;
            short8 ah = *(const short8*)(w1fh + ((size_t)(l * 4 + mtg) * 64 + lane) * 8);
            short8 al = *(const short8*)(w1fl + ((size_t)(l * 4 + mtg) * 64 + lane) * 8);
            f32x4 a1[8];
#pragma unroll
            for (int i = 0; i < 8; ++i) {
                f32x4 t = (f32x4)0.f;
                t = __builtin_amdgcn_mfma_f32_16x16x32_bf16(ah, Bh[i], t, 0, 0, 0);
                t = __builtin_amdgcn_mfma_f32_16x16x32_bf16(al, Bh[i], t, 0, 0, 0);
                a1[i] = t;
            }
            float4 bias4 = *(const float4*)(cb1 + l * 64 + mtg * 16 + fq * 4);
            float bb[4] = {bias4.x, bias4.y, bias4.z, bias4.w};
#pragma unroll
            for (int Rg = 0; Rg < 2; ++Rg) {
                ushort hb[4];
#pragma unroll
                for (int j2 = 0; j2 < 4; ++j2) {
                    float m0 = fmaxf(fmaxf(a1[Rg * 4 + 0][j2], a1[Rg * 4 + 1][j2]),
                                     fmaxf(a1[Rg * 4 + 2][j2], a1[Rg * 4 + 3][j2]));
                    float v = fmaxf(m0 + bb[j2], 0.f);
                    hb[j2] = f2bf(v);
                }
                int pr = 2 * wid + Rg;
                int off = ((pr + 1) * 18 + (fr + 1)) * ICST + mt2 * 16 + fq * 4;
                uint2 H;
                H.x = (uint)hb[0] | ((uint)hb[1] << 16);
                H.y = (uint)hb[2] | ((uint)hb[3] << 16);
                *(uint2*)&yt[off] = H;
            }
        }
        __syncthreads();   // drains vmcnt (gll complete) + y writes visible

        // ---- conv2 phase: dc-major, single-plane A from LDS, input-row reuse ----
#pragma unroll
        for (int dc = 0; dc < 3; ++dc) {
            short8 Ah[2][3];
#pragma unroll
            for (int dr = 0; dr < 3; ++dr) {
                int tap = dr * 3 + dc;
#pragma unroll
                for (int m = 0; m < 2; ++m) {
                    int mt = 2 * g + m;
                    Ah[m][dr] = *(const short8*)&wlds[((tap * 4 + mt) * 64 + lane) * 8];
                }
            }
#pragma unroll
            for (int rr = 0; rr < 6; ++rr) {
                int off = ((4 * ng + rr) * 18 + (fr + dc)) * ICST + fq * 8;
                short8 bh = *(const short8*)(yt + off);
#pragma unroll
                for (int dr = 0; dr < 3; ++dr) {
                    int rl = rr - dr;
                    if (rl >= 0 && rl < 4) {
#pragma unroll
                        for (int m = 0; m < 2; ++m) {
                            acc[m][rl] = __builtin_amdgcn_mfma_f32_16x16x32_bf16(Ah[m][dr], bh, acc[m][rl], 0, 0, 0);
                        }
                    }
                }
            }
        }
        if (icc) {  // leaf epilogue: bias + relu + mixture accumulate
            float mx = mixw[(size_t)b * 8 + l];
#pragma unroll
            for (int m = 0; m < 2; ++m)
#pragma unroll
                for (int j = 0; j < 4; ++j) {
                    float bias = cb2[l * 64 + (2 * g + m) * 16 + fq * 4 + j];
#pragma unroll
                    for (int rl = 0; rl < 4; ++rl) {
                        float v = fmaxf(acc[m][rl][j] + bias, 0.f);
                        oacc[m][rl][j] = fmaf(mx, v, oacc[m][rl][j]);
                        acc[m][rl][j] = 0.f;
                    }
                }
        }
        __syncthreads();   // protect y + wlds before next step's gll/writes
    }

    // ---- store out1 [bl][64 oc][256 pos] fp32 ----
#pragma unroll
    for (int m = 0; m < 2; ++m)
#pragma unroll
        for (int rl = 0; rl < 4; ++rl)
#pragma unroll
            for (int j = 0; j < 4; ++j) {
                int oc = (2 * g + m) * 16 + fq * 4 + j;
                int pos = (4 * ng + rl) * 16 + fr;
                out1[((size_t)bl * 64 + oc) * 256 + pos] = oacc[m][rl][j];
            }
}

// ---------- fc: [bc][16384] @ [10][16384]^T + b ----------
__global__ __launch_bounds__(256) void k_fc(const float* __restrict__ out1, const float* __restrict__ fcw,
                                            const float* __restrict__ fcb, float* __restrict__ out, int boff) {
    __shared__ float red[4][OUTW_];
    int tid = threadIdx.x;
    int bl = blockIdx.x;
    const float4* flat = (const float4*)(out1 + (size_t)bl * FCIN_);
    float pj[OUTW_];
#pragma unroll
    for (int j = 0; j < OUTW_; ++j) pj[j] = 0.f;
    for (int i = tid; i < FCIN_ / 4; i += 256) {
        float4 v = flat[i];
#pragma unroll
        for (int j = 0; j < OUTW_; ++j) {
            float4 w = ((const float4*)(fcw + (size_t)j * FCIN_))[i];
            pj[j] += v.x * w.x + v.y * w.y + v.z * w.z + v.w * w.w;
        }
    }
#pragma unroll
    for (int j = 0; j < OUTW_; ++j) {
        float v = pj[j];
        for (int off = 32; off > 0; off >>= 1) v += __shfl_xor(v, off);
        if ((tid & 63) == 0) red[tid >> 6][j] = v;
    }
    __syncthreads();
    if (tid < OUTW_) {
        float s = red[0][tid] + red[1][tid] + red[2][tid] + red[3][tid] + fcb[tid];
        out[(size_t)(boff + bl) * OUTW_ + tid] = s;
    }
}

extern "C" void kernel_launch(void* const* d_in, const int* in_sizes, int n_in,
                              void* d_out, int out_size, void* d_ws, size_t ws_size,
                              hipStream_t stream) {
    const float* x   = (const float*)d_in[0];
    const float* nw  = (const float*)d_in[1];
    const float* nb  = (const float*)d_in[2];
    const float* w1  = (const float*)d_in[3];
    const float* cb1 = (const float*)d_in[4];
    const float* w2  = (const float*)d_in[5];
    const float* cb2 = (const float*)d_in[6];
    const float* fcw = (const float*)d_in[7];
    const float* fcb = (const float*)d_in[8];
    float* out = (float*)d_out;

    float*  ws   = (float*)d_ws;
    float*  mix  = ws;                        // 2048 f
    ushort* w1fh = (ushort*)(mix + 2048);     // 16384 us
    ushort* w1fl = w1fh + 16384;              // 16384 us
    ushort* w2r  = w1fl + 16384;              // 294912 us ([l][icc][tap][mt][lane][j8] single plane)
    float*  out1 = (float*)(w2r + 294912);    // Bc * 16384 f

    // fixed bytes: 2048*4 + 2*16384*2 + 294912*2 = 663552; out1 per sample = 65536 B
    long avail = (long)ws_size - 663552L;
    int Bc = (int)(avail / 65536L);
    if (Bc > B_) Bc = B_;
    if (Bc < 1) Bc = 1;

    k_prep<<<1472, 256, 0, stream>>>(w1, w1fh, w1fl, w2, w2r, x, nw, nb, mix);

    for (int boff = 0; boff < B_; boff += Bc) {
        int bc = (B_ - boff < Bc) ? (B_ - boff) : Bc;
        k_fused<<<bc, 512, 0, stream>>>(x, w1fh, w1fl, cb1, w2r, cb2, mix, out1, boff);
        k_fc<<<bc, 256, 0, stream>>>(out1, fcw, fcb, out, boff);
    }
}

// Round 17
// 81.245 us; speedup vs baseline: 2.2699x; 1.0164x over previous
//
#include <hip/hip_runtime.h>
#include <cstdint>
#include <cstddef>

#define B_ 256
#define IW_ 3072
#define L_ 8
#define NN_ 7
#define FCIN_ 16384
#define OUTW_ 10
#define ICST 72            // ushorts per (row,col) cell: 64 ic + 8 pad (144B = 9 granules, odd -> spread)
#define YPLANE (324 * ICST)   // 23328 us = 46.7 KB
#define WCH 36864          // ushorts per leaf W2 chunk: [icc2][tap9][mt4][lane64][j8] single RTN plane = 72 KB

typedef short short8 __attribute__((ext_vector_type(8)));
typedef float f32x4 __attribute__((ext_vector_type(4)));

__device__ __forceinline__ ushort f2bf(float x) {
    uint u = __float_as_uint(x);
    return (ushort)((u + 0x7fffu + ((u >> 16) & 1u)) >> 16);
}
__device__ __forceinline__ float bf2f(ushort b) { return __uint_as_float(((uint)b) << 16); }

// ---------- merged prep: [0,64) w1 repack | [64,1216) w2 repack | [1216,1472) mixture ----------
__global__ __launch_bounds__(256) void k_prep(const float* __restrict__ w1, ushort* __restrict__ w1fr,
                                              const float* __restrict__ w2, ushort* __restrict__ w2r,
                                              const float* __restrict__ x, const float* __restrict__ nw,
                                              const float* __restrict__ nb, float* __restrict__ mix) {
    int blk = blockIdx.x;
    if (blk < 64) {
        // conv1 weights -> frag-linear single RTN plane: [l8][mt4][lane64][j8]
        int i = blk * 256 + threadIdx.x;
        int j    = i & 7;
        int lane = (i >> 3) & 63;
        int mt   = (i >> 9) & 3;
        int l    = i >> 11;
        int fr = lane & 15, fq = lane >> 4;
        int oc = mt * 16 + fr;
        int k = fq * 8 + j;
        float w = (k < 27) ? w1[(size_t)(l * 64 + oc) * 27 + k] : 0.f;
        w1fr[i] = f2bf(w);
        return;
    }
    if (blk < 1216) {
        // conv2 weights -> [l8][icc2][tap9][mt4][lane64][j8], single RTN bf16 plane
        int i = (blk - 64) * 256 + threadIdx.x;
        int j     = i & 7;
        int lane  = (i >> 3) & 63;
        int mt    = (i >> 9) & 3;
        int tap   = (i >> 11) % 9;
        int icc   = (i / 18432) & 1;
        int l     = i / 36864;
        int fr = lane & 15, fq = lane >> 4;
        int oc = mt * 16 + fr;
        int ic = icc * 32 + fq * 8 + j;
        float w = w2[(((size_t)l * 64 + oc) * 64 + ic) * 9 + tap];
        w2r[i] = f2bf(w);
        return;
    }
    // mixture
    __shared__ float red[4 * NN_];
    __shared__ float bes[NN_];
    int b = blk - 1216, tid = threadIdx.x;
    const float* xb = x + (size_t)b * IW_;
    float p[NN_];
#pragma unroll
    for (int n = 0; n < NN_; ++n) p[n] = 0.f;
    for (int i = tid; i < IW_; i += 256) {
        float xv = xb[i];
#pragma unroll
        for (int n = 0; n < NN_; ++n) p[n] = fmaf(xv, nw[n * IW_ + i], p[n]);
    }
#pragma unroll
    for (int n = 0; n < NN_; ++n) {
        float v = p[n];
        for (int off = 32; off > 0; off >>= 1) v += __shfl_xor(v, off);
        if ((tid & 63) == 0) red[(tid >> 6) * NN_ + n] = v;
    }
    __syncthreads();
    if (tid < NN_) {
        float s = red[tid] + red[NN_ + tid] + red[2 * NN_ + tid] + red[3 * NN_ + tid] + nb[tid];
        bes[tid] = 1.f / (1.f + expf(-s));
    }
    __syncthreads();
    if (tid < L_) {
        int leaf = tid;
        float b0 = bes[0];
        float t0 = ((leaf >> 2) & 1) ? b0 : 1.f - b0;
        float b1v = bes[1 + ((leaf >> 2) & 1)];
        float t1 = ((leaf >> 1) & 1) ? b1v : 1.f - b1v;
        float b2v = bes[3 + ((leaf >> 1) & 3)];
        float t2 = (leaf & 1) ? b2v : 1.f - b2v;
        mix[b * L_ + leaf] = t0 * t1 * t2;
    }
}

// ---------- fused conv1/conv2: full-leaf steps, single-plane W1 & W2 ----------
// block = sample (grid 256 = 1/CU), 512 thr / 8 waves, 8 steps (one per leaf).
// Step: issue gll (72KB leaf W2 chunk, DMA global->LDS, hides under conv1) ->
// conv1 MFMA all 64 chans (RTN W1 x RTN im2col, 1 product) + in-lane 2x2 pool ->
// barrier -> conv2 dc-major MFMA over full K=64 (2 icc sub-chunks) -> leaf epilogue -> barrier.
// 16 barriers total (was 32); phases 2x longer to amortize 2-waves/SIMD latency slack.
__global__ __launch_bounds__(512, 1) void k_fused(const float* __restrict__ x,
                                                  const ushort* __restrict__ w1fr,
                                                  const float* __restrict__ cb1,
                                                  const ushort* __restrict__ w2r,
                                                  const float* __restrict__ cb2, const float* __restrict__ mixw,
                                                  float* __restrict__ out1, int boff) {
    __shared__ __align__(16) ushort smem[YPLANE + WCH];   // yt 46.7 KB | wlds 72 KB = 117.6 KB
    ushort* yt = smem;
    ushort* wlds = smem + YPLANE;
    float* xpad = (float*)smem;                            // prologue-only alias (13.9 KB < yt)

    int tid = threadIdx.x;
    int bl = blockIdx.x;
    int b = boff + bl;
    int lane = tid & 63, wid = tid >> 6;
    int fr = lane & 15, fq = lane >> 4;
    int g = wid & 1, ng = wid >> 1;               // conv2: mts {2g,2g+1}, rows {4ng..4ng+3}

    // ---- prologue: xpad zero + fill ----
    for (int i = tid; i < 3 * 34 * 34; i += 512) xpad[i] = 0.f;
    __syncthreads();
    for (int i = tid; i < 3072; i += 512) {
        int ch = i >> 10, rr = (i >> 5) & 31, cc = i & 31;
        xpad[(ch * 34 + rr + 1) * 34 + cc + 1] = x[(size_t)b * IW_ + i];
    }
    __syncthreads();

    // ---- leaf-invariant conv1 im2col B-frags (pool-window-in-lane mapping) ----
    short8 Bh[8];
#pragma unroll
    for (int i = 0; i < 8; ++i) {
        int Rg = i >> 2;                 // pooled row within wave pair
        int subrow = (i >> 1) & 1;       // pre-pool row within 2x2 window
        int parity = i & 1;              // pre-pool col parity
        int prow = (wid * 2 + Rg) * 2 + subrow;   // 0..31
        int pcol = 2 * fr + parity;               // 0..31
#pragma unroll
        for (int j = 0; j < 8; ++j) {
            int k = fq * 8 + j;          // k = ic*9 + tap
            float xv = 0.f;
            if (k < 27) {
                int ic = k / 9;
                int tap = k - ic * 9;
                int dr = tap / 3, dc = tap - dr * 3;
                xv = xpad[(ic * 34 + prow + dr) * 34 + (pcol + dc)];
            }
            Bh[i][j] = (short)f2bf(xv);
        }
    }
    __syncthreads();
    {   // zero y plane (borders stay zero forever)
        uint4 z; z.x = z.y = z.z = z.w = 0u;
        for (int i = tid; i < YPLANE / 8; i += 512) ((uint4*)yt)[i] = z;
    }
    __syncthreads();

    f32x4 acc[2][4], oacc[2][4];
#pragma unroll
    for (int m = 0; m < 2; ++m)
#pragma unroll
        for (int rl = 0; rl < 4; ++rl) { acc[m][rl] = (f32x4)0.f; oacc[m][rl] = (f32x4)0.f; }

    for (int l = 0; l < 8; ++l) {
        // ---- async-stage this leaf's 72KB W2 chunk via global_load_lds (hides under conv1) ----
        {
            const char* wsrc = (const char*)(w2r + (size_t)l * WCH);
#pragma unroll
            for (int r = 0; r < 9; ++r) {
                int idx = r * 8 + wid;                 // 0..71 wave-loads of 1KB
                const char* gp = wsrc + idx * 1024 + lane * 16;
                __builtin_amdgcn_global_load_lds(
                    (const __attribute__((address_space(1))) uint*)gp,
                    (__attribute__((address_space(3))) uint*)((char*)wlds + idx * 1024),
                    16, 0, 0);
            }
        }

        // ---- conv1 phase: all 64 chans (4 mtiles), single-plane W1, in-lane pool ----
#pragma unroll
        for (int mtg = 0; mtg < 4; ++mtg) {
            short8 ah = *(const short8*)(w1fr + ((size_t)(l * 4 + mtg) * 64 + lane) * 8);
            f32x4 a1[8];
#pragma unroll
            for (int i = 0; i < 8; ++i) {
                f32x4 t = (f32x4)0.f;
                t = __builtin_amdgcn_mfma_f32_16x16x32_bf16(ah, Bh[i], t, 0, 0, 0);
                a1[i] = t;
            }
            float4 bias4 = *(const float4*)(cb1 + l * 64 + mtg * 16 + fq * 4);
            float bb[4] = {bias4.x, bias4.y, bias4.z, bias4.w};
#pragma unroll
            for (int Rg = 0; Rg < 2; ++Rg) {
                ushort hb[4];
#pragma unroll
                for (int j2 = 0; j2 < 4; ++j2) {
                    float m0 = fmaxf(fmaxf(a1[Rg * 4 + 0][j2], a1[Rg * 4 + 1][j2]),
                                     fmaxf(a1[Rg * 4 + 2][j2], a1[Rg * 4 + 3][j2]));
                    float v = fmaxf(m0 + bb[j2], 0.f);
                    hb[j2] = f2bf(v);
                }
                int pr = 2 * wid + Rg;
                int off = ((pr + 1) * 18 + (fr + 1)) * ICST + mtg * 16 + fq * 4;
                uint2 H;
                H.x = (uint)hb[0] | ((uint)hb[1] << 16);
                H.y = (uint)hb[2] | ((uint)hb[3] << 16);
                *(uint2*)&yt[off] = H;
            }
        }
        __syncthreads();   // drains vmcnt (gll complete) + y writes visible

        // ---- conv2 phase: dc-major, full K=64 (2 icc sub-chunks), input-row reuse ----
#pragma unroll
        for (int dc = 0; dc < 3; ++dc) {
#pragma unroll
            for (int icc = 0; icc < 2; ++icc) {
                short8 Ah[2][3];
#pragma unroll
                for (int dr = 0; dr < 3; ++dr) {
                    int tap = dr * 3 + dc;
#pragma unroll
                    for (int m = 0; m < 2; ++m) {
                        int mt = 2 * g + m;
                        Ah[m][dr] = *(const short8*)&wlds[(((icc * 9 + tap) * 4 + mt) * 64 + lane) * 8];
                    }
                }
#pragma unroll
                for (int rr = 0; rr < 6; ++rr) {
                    int off = ((4 * ng + rr) * 18 + (fr + dc)) * ICST + icc * 32 + fq * 8;
                    short8 bh = *(const short8*)(yt + off);
#pragma unroll
                    for (int dr = 0; dr < 3; ++dr) {
                        int rl = rr - dr;
                        if (rl >= 0 && rl < 4) {
#pragma unroll
                            for (int m = 0; m < 2; ++m) {
                                acc[m][rl] = __builtin_amdgcn_mfma_f32_16x16x32_bf16(Ah[m][dr], bh, acc[m][rl], 0, 0, 0);
                            }
                        }
                    }
                }
            }
        }
        {   // leaf epilogue: bias + relu + mixture accumulate
            float mx = mixw[(size_t)b * 8 + l];
#pragma unroll
            for (int m = 0; m < 2; ++m)
#pragma unroll
                for (int j = 0; j < 4; ++j) {
                    float bias = cb2[l * 64 + (2 * g + m) * 16 + fq * 4 + j];
#pragma unroll
                    for (int rl = 0; rl < 4; ++rl) {
                        float v = fmaxf(acc[m][rl][j] + bias, 0.f);
                        oacc[m][rl][j] = fmaf(mx, v, oacc[m][rl][j]);
                        acc[m][rl][j] = 0.f;
                    }
                }
        }
        __syncthreads();   // protect y + wlds before next leaf's gll/writes
    }

    // ---- store out1 [bl][64 oc][256 pos] fp32 ----
#pragma unroll
    for (int m = 0; m < 2; ++m)
#pragma unroll
        for (int rl = 0; rl < 4; ++rl)
#pragma unroll
            for (int j = 0; j < 4; ++j) {
                int oc = (2 * g + m) * 16 + fq * 4 + j;
                int pos = (4 * ng + rl) * 16 + fr;
                out1[((size_t)bl * 64 + oc) * 256 + pos] = oacc[m][rl][j];
            }
}

// ---------- fc: [bc][16384] @ [10][16384]^T + b ----------
__global__ __launch_bounds__(256) void k_fc(const float* __restrict__ out1, const float* __restrict__ fcw,
                                            const float* __restrict__ fcb, float* __restrict__ out, int boff) {
    __shared__ float red[4][OUTW_];
    int tid = threadIdx.x;
    int bl = blockIdx.x;
    const float4* flat = (const float4*)(out1 + (size_t)bl * FCIN_);
    float pj[OUTW_];
#pragma unroll
    for (int j = 0; j < OUTW_; ++j) pj[j] = 0.f;
    for (int i = tid; i < FCIN_ / 4; i += 256) {
        float4 v = flat[i];
#pragma unroll
        for (int j = 0; j < OUTW_; ++j) {
            float4 w = ((const float4*)(fcw + (size_t)j * FCIN_))[i];
            pj[j] += v.x * w.x + v.y * w.y + v.z * w.z + v.w * w.w;
        }
    }
#pragma unroll
    for (int j = 0; j < OUTW_; ++j) {
        float v = pj[j];
        for (int off = 32; off > 0; off >>= 1) v += __shfl_xor(v, off);
        if ((tid & 63) == 0) red[tid >> 6][j] = v;
    }
    __syncthreads();
    if (tid < OUTW_) {
        float s = red[0][tid] + red[1][tid] + red[2][tid] + red[3][tid] + fcb[tid];
        out[(size_t)(boff + bl) * OUTW_ + tid] = s;
    }
}

extern "C" void kernel_launch(void* const* d_in, const int* in_sizes, int n_in,
                              void* d_out, int out_size, void* d_ws, size_t ws_size,
                              hipStream_t stream) {
    const float* x   = (const float*)d_in[0];
    const float* nw  = (const float*)d_in[1];
    const float* nb  = (const float*)d_in[2];
    const float* w1  = (const float*)d_in[3];
    const float* cb1 = (const float*)d_in[4];
    const float* w2  = (const float*)d_in[5];
    const float* cb2 = (const float*)d_in[6];
    const float* fcw = (const float*)d_in[7];
    const float* fcb = (const float*)d_in[8];
    float* out = (float*)d_out;

    float*  ws   = (float*)d_ws;
    float*  mix  = ws;                        // 2048 f
    ushort* w1fr = (ushort*)(mix + 2048);     // 16384 us (single RTN plane)
    ushort* w2r  = w1fr + 16384;              // 294912 us ([l][icc][tap][mt][lane][j8] single plane)
    float*  out1 = (float*)(w2r + 294912);    // Bc * 16384 f

    // fixed bytes: 2048*4 + 16384*2 + 294912*2 = 630784; out1 per sample = 65536 B
    long avail = (long)ws_size - 630784L;
    int Bc = (int)(avail / 65536L);
    if (Bc > B_) Bc = B_;
    if (Bc < 1) Bc = 1;

    k_prep<<<1472, 256, 0, stream>>>(w1, w1fr, w2, w2r, x, nw, nb, mix);

    for (int boff = 0; boff < B_; boff += Bc) {
        int bc = (B_ - boff < Bc) ? (B_ - boff) : Bc;
        k_fused<<<bc, 512, 0, stream>>>(x, w1fr, cb1, w2r, cb2, mix, out1, boff);
        k_fc<<<bc, 256, 0, stream>>>(out1, fcw, fcb, out, boff);
    }
}